// Round 10
// baseline (299.113 us; speedup 1.0000x reference)
//
#include <hip/hip_runtime.h>
#include <hip/hip_bf16.h>

#define BB 2
#define TT 4096
#define DD 128
#define KK 256
#define NROW (BB*TT)    // 8192 rows
#define NELT (NROW*DD)  // 1048576 elements per [B,T,D] buffer

typedef _Float16 f16;
typedef __attribute__((ext_vector_type(8))) f16 half8;
typedef __attribute__((ext_vector_type(2))) __fp16 fp16x2;
typedef __attribute__((ext_vector_type(4))) float f32x4;
typedef __attribute__((ext_vector_type(16))) float f32x16;
typedef __attribute__((ext_vector_type(2))) int i32x2;
typedef __attribute__((ext_vector_type(4))) int i32x4;

__device__ __forceinline__ int pack2(float a, float b){
  fp16x2 h = __builtin_amdgcn_cvt_pkrtz(a, b);
  return __builtin_bit_cast(int, h);
}

// ---- stage a 128x128 f32 weight matrix into LDS as fp16 (32 KB), 256 threads ----
__device__ __forceinline__ void stage_w_f16(int tid, const float* __restrict__ W, f16* Wh){
  #pragma unroll
  for (int it = 0; it < 8; it++){
    int idx = tid + it*256;               // 2048 half8 chunks
    f32x4 a = *(const f32x4*)(W + (size_t)idx*8);
    f32x4 b = *(const f32x4*)(W + (size_t)idx*8 + 4);
    half8 h;
    #pragma unroll
    for (int u = 0; u < 4; u++){ h[u] = (f16)a[u]; h[4+u] = (f16)b[u]; }
    *(half8*)(Wh + (size_t)idx*8) = h;
  }
}

// ---- shared helper: 32-row fp32 matvec (fp16 W in LDS) + normalize -> fp16 rows (+transpose)
__device__ __forceinline__ void proj_norm_rows(
    int tid, int r0,
    const float* __restrict__ src, const float* __restrict__ W, const float* __restrict__ bias,
    f16* __restrict__ dst, f16* __restrict__ dstT)
{
  __shared__ f16 Wh[DD*DD];      // 32 KB
  __shared__ float zs[32*DD];    // 16 KB
  stage_w_f16(tid, W, Wh);
  #pragma unroll
  for (int it = 0; it < 4; it++){
    int idx = tid + it*256;
    *(f32x4*)(zs + idx*4) = *(const f32x4*)(src + (size_t)r0*DD + idx*4);
  }
  __syncthreads();
  int c = tid & 15, rr = tid >> 4;
  float acc0[8], acc1[8];
  #pragma unroll
  for (int u = 0; u < 8; u++){ float bv = bias[c*8+u]; acc0[u] = bv; acc1[u] = bv; }
  const float* zr0 = zs + rr*DD;
  const float* zr1 = zs + (rr+16)*DD;
  #pragma unroll 4
  for (int i = 0; i < DD; i++){
    half8 wv = *(const half8*)(Wh + i*DD + c*8);
    float a0 = zr0[i], a1 = zr1[i];
    #pragma unroll
    for (int u = 0; u < 8; u++){
      float w = (float)wv[u];
      acc0[u] = fmaf(a0, w, acc0[u]);
      acc1[u] = fmaf(a1, w, acc1[u]);
    }
  }
  float s0 = 0.f, s1 = 0.f;
  #pragma unroll
  for (int u = 0; u < 8; u++){ s0 = fmaf(acc0[u], acc0[u], s0); s1 = fmaf(acc1[u], acc1[u], s1); }
  #pragma unroll
  for (int m = 1; m < 16; m <<= 1){ s0 += __shfl_xor(s0, m, 16); s1 += __shfl_xor(s1, m, 16); }
  float inv0 = 1.f / fmaxf(sqrtf(s0), 1e-8f);
  float inv1 = 1.f / fmaxf(sqrtf(s1), 1e-8f);
  half8 h0, h1;
  #pragma unroll
  for (int u = 0; u < 8; u++){ h0[u] = (f16)(acc0[u]*inv0); h1[u] = (f16)(acc1[u]*inv1); }
  int row0 = r0 + rr, row1 = row0 + 16;
  *(half8*)(dst + (size_t)row0*DD + c*8) = h0;
  *(half8*)(dst + (size_t)row1*DD + c*8) = h1;
  if (dstT){
    int b = row0 >> 12, t0 = row0 & 4095, t1 = row1 & 4095;
    #pragma unroll
    for (int u = 0; u < 8; u++){
      dstT[((size_t)b*DD + c*8 + u)*TT + t0] = h0[u];
      dstT[((size_t)b*DD + c*8 + u)*TT + t1] = h1[u];
    }
  }
}

// ======== k_prep: blocks 0..511: conv; 512..767: k-proj; 768..1023: q0-proj; 1024: WoT ==
__global__ __launch_bounds__(256) void k_prep(
    const float* __restrict__ z, const float* __restrict__ Wk, const float* __restrict__ bk,
    const float* __restrict__ ck, const float* __restrict__ cb,
    const float* __restrict__ Wq, const float* __restrict__ bq,
    const float* __restrict__ Wo,
    f16* __restrict__ khb, f16* __restrict__ khT, f16* __restrict__ qhb,
    float* __restrict__ mf, f16* __restrict__ woT)
{
  int tid = threadIdx.x;
  if (blockIdx.x < 512){
    int bid = blockIdx.x;
    int d = tid & 127, tg = tid >> 7;
    int b = bid >> 8;
    int tbase = ((bid & 255) << 4) + tg*8;
    const float* zb = z + (size_t)b*TT*DD;
    float acc[8];
    #pragma unroll
    for (int j = 0; j < 8; j++) acc[j] = 0.f;
    float ckq[8];
    #pragma unroll
    for (int u = 0; u < 8; u++) ckq[u] = 0.f;
    int sstart = tbase - (KK-1);
    for (int ch = 0; ch < 33; ch++){
      #pragma unroll
      for (int u = 0; u < 8; u++){
        int base = ch*8 + u;
        int s = sstart + base;
        float zv = ((unsigned)s < (unsigned)TT && base < 263) ? zb[(size_t)s*DD + d] : 0.f;
        ckq[u] = (base < KK) ? ck[(size_t)base*DD + d] : 0.f;
        #pragma unroll
        for (int j = 0; j < 8; j++) acc[j] = fmaf(ckq[(u-j)&7], zv, acc[j]);
      }
    }
    float cbv = cb[d];
    #pragma unroll
    for (int j = 0; j < 8; j++)
      mf[((size_t)b*TT + tbase + j)*DD + d] = acc[j] + cbv;
  } else if (blockIdx.x < 768){
    proj_norm_rows(tid, (blockIdx.x - 512) * 32, z, Wk, bk, khb, khT);
  } else if (blockIdx.x < 1024){
    proj_norm_rows(tid, (blockIdx.x - 768) * 32, z, Wq, bq, qhb, nullptr);
  } else {
    // ---- one-shot WoT fp16: woT[odim j][idim i] = Wo[i][j] ----
    int j  = tid >> 1;          // 0..127
    int ib = tid & 1;           // 0/1
    #pragma unroll
    for (int u = 0; u < 8; u++){
      int i0 = ib*64 + u*8;
      half8 h;
      #pragma unroll
      for (int k = 0; k < 8; k++) h[k] = (f16)Wo[(size_t)(i0+k)*DD + j];
      *(half8*)(woT + (size_t)j*DD + i0) = h;
    }
  }
}

// ====== MFMA attention v20: CH=4 (544 blocks -> uniform 2 blocks/CU), fp16 kur partials,
//        Wo epilogue reads precomputed WoT frags straight from global (no staging/barriers) ==
#define QTILE 128
#define NQT3 (TT/QTILE)     // 32 q-tiles per batch
#define NCHUNK 272          // per batch: sum_{qt} ceil((2qt+2)/4)

__global__ __launch_bounds__(256,2) void k_attn20(
    const f16* __restrict__ qhb, const f16* __restrict__ khb,
    const f16* __restrict__ khT, const f16* __restrict__ woT,
    f16* __restrict__ part)
{
  int bid = blockIdx.x;
  int b = bid / NCHUNK;
  int rem = bid - b*NCHUNK;
  int qt = 0, chunk = 0;
  #pragma unroll 1
  for (int j = NQT3-1; j >= 0; j--){
    int nch = (2*j + 5) >> 2;   // ceil((2j+2)/4)
    if (rem < nch){ qt = j; chunk = rem; break; }
    rem -= nch;
  }
  int kt0 = chunk * 4;
  int kt1 = min(kt0 + 3, 2*qt + 1);
  int t0 = qt * QTILE;

  __shared__ __align__(16) f16 KbD[2][64*136];   // [key][dim], stride 136
  __shared__ __align__(16) f16 KtD[2][128*72];   // [dim][key], stride 72

  int tid  = threadIdx.x;
  int w    = tid >> 6;        // 4 waves, wave w owns q-rows 32w..32w+31
  int lane = tid & 63;
  int q31  = lane & 31;
  int hi   = lane >> 5;

  const f16* qg  = qhb + (size_t)b*TT*DD;
  const f16* kg  = khb + (size_t)b*TT*DD;
  const f16* ktg = khT + (size_t)b*DD*TT;

  int sb_r  = tid >> 4, sb_c = (tid & 15)*8;   // Kb staging
  int st_r  = tid >> 3, st_c = (tid & 7)*8;    // Kt staging

  int qrow_g = t0 + 32*w + q31;

  // Q fragments (B-operand): lane holds Q[qrow_g][16ks + 8hi + 0..7]
  half8 qb[8];
  {
    const f16* qrow = qg + (size_t)qrow_g*DD + 8*hi;
    #pragma unroll
    for (int ks = 0; ks < 8; ks++) qb[ks] = *(const half8*)(qrow + 16*ks);
  }

  // acc = O^T: acc[d0][r] = O^T[dim=32d0+(r&3)+8(r>>2)+4hi][q=q31]
  f32x16 acc[4];
  #pragma unroll
  for (int d = 0; d < 4; d++)
    #pragma unroll
    for (int i = 0; i < 16; i++) acc[d][i] = 0.f;

  // ---- prologue: stage first tile ----
  half8 sKb[4], sKt[4];
  {
    int s0 = kt0 * 64;
    #pragma unroll
    for (int it = 0; it < 4; it++)
      sKb[it] = *(const half8*)(kg + (size_t)(s0 + sb_r + it*16)*DD + sb_c);
    #pragma unroll
    for (int it = 0; it < 4; it++)
      sKt[it] = *(const half8*)(ktg + (size_t)(st_r + it*32)*TT + s0 + st_c);
    #pragma unroll
    for (int it = 0; it < 4; it++)
      *(half8*)(&KbD[0][0] + (sb_r + it*16)*136 + sb_c) = sKb[it];
    #pragma unroll
    for (int it = 0; it < 4; it++)
      *(half8*)(&KtD[0][0] + (st_r + it*32)*72 + st_c) = sKt[it];
  }
  __syncthreads();

  #pragma unroll 1
  for (int kt = kt0; kt <= kt1; kt++){
    int cur = (kt - kt0) & 1;
    const f16* KbL = &KbD[cur][0];
    const f16* KtL = &KtD[cur][0];

    // issue next tile's global loads first (latency hides under compute)
    if (kt < kt1){
      int s0n = (kt+1) * 64;
      #pragma unroll
      for (int it = 0; it < 4; it++)
        sKb[it] = *(const half8*)(kg + (size_t)(s0n + sb_r + it*16)*DD + sb_c);
      #pragma unroll
      for (int it = 0; it < 4; it++)
        sKt[it] = *(const half8*)(ktg + (size_t)(st_r + it*32)*TT + s0n + st_c);
    }

    int s0 = kt * 64;
    // ---- QK^T: A = K rows (LDS b128), B = Q regs -> S^T[key32][q32] x2 ----
    f32x16 sa0, sa1;
    #pragma unroll
    for (int i = 0; i < 16; i++){ sa0[i] = 0.f; sa1[i] = 0.f; }
    #pragma unroll
    for (int ks = 0; ks < 8; ks++){
      half8 a0 = *(const half8*)(KbL + (q31)      *136 + 16*ks + 8*hi);
      half8 a1 = *(const half8*)(KbL + (32 + q31) *136 + 16*ks + 8*hi);
      sa0 = __builtin_amdgcn_mfma_f32_32x32x16_f16(a0, qb[ks], sa0, 0,0,0);
      sa1 = __builtin_amdgcn_mfma_f32_32x32x16_f16(a1, qb[ks], sa1, 0,0,0);
    }

    // ---- sin + causal mask, in-register ----
    float p0v[16], p1v[16];
    #pragma unroll
    for (int r = 0; r < 16; r++){
      int kr = (r&3) + 8*(r>>2) + 4*hi;
      p0v[r] = (s0 + kr      <= qrow_g) ? __sinf(sa0[r]) : 0.f;
      p1v[r] = (s0 + 32 + kr <= qrow_g) ? __sinf(sa1[r]) : 0.f;
    }

    // ---- in-register P regroup (cvt_pk + shfl_xor(32)) ----
    half8 pf[4];
    #pragma unroll
    for (int kb = 0; kb < 2; kb++){
      const float* pv = kb ? p1v : p0v;
      #pragma unroll
      for (int u = 0; u < 2; u++){
        int pl0 = pack2(pv[8*u+0], pv[8*u+1]);
        int pl1 = pack2(pv[8*u+2], pv[8*u+3]);
        int ph0 = pack2(pv[8*u+4], pv[8*u+5]);
        int ph1 = pack2(pv[8*u+6], pv[8*u+7]);
        int xl0 = __shfl_xor(pl0, 32);
        int xl1 = __shfl_xor(pl1, 32);
        int xh0 = __shfl_xor(ph0, 32);
        int xh1 = __shfl_xor(ph1, 32);
        i32x4 fr;
        fr[0] = hi ? xh0 : pl0;
        fr[1] = hi ? xh1 : pl1;
        fr[2] = hi ? ph0 : xl0;
        fr[3] = hi ? ph1 : xl1;
        pf[2*kb+u] = __builtin_bit_cast(half8, fr);
      }
    }

    // ---- PV swapped: A = Kt rows, B = P frags -> O^T[dim32][q32] x4 ----
    #pragma unroll
    for (int s = 0; s < 4; s++){
      #pragma unroll
      for (int d0 = 0; d0 < 4; d0++){
        half8 bf = *(const half8*)(KtL + (32*d0 + q31)*72 + 16*s + 8*hi);
        acc[d0] = __builtin_amdgcn_mfma_f32_32x32x16_f16(bf, pf[s], acc[d0], 0,0,0);
      }
    }

    // ---- write next tile into the other LDS buffer; single barrier per tile ----
    if (kt < kt1){
      f16* KbN = &KbD[cur^1][0];
      f16* KtN = &KtD[cur^1][0];
      #pragma unroll
      for (int it = 0; it < 4; it++)
        *(half8*)(KbN + (sb_r + it*16)*136 + sb_c) = sKb[it];
      #pragma unroll
      for (int it = 0; it < 4; it++)
        *(half8*)(KtN + (st_r + it*32)*72 + st_c) = sKt[it];
      __syncthreads();
    }
  }

  // ====== fused Wo projection: kur^T = Wo^T @ O^T; WoT frags direct from global (L2) ======
  // O^T -> fp16 B-frags (same regroup as P)
  half8 bO[8];
  #pragma unroll
  for (int d0 = 0; d0 < 4; d0++){
    #pragma unroll
    for (int m = 0; m < 2; m++){
      int pl0 = pack2(acc[d0][8*m+0], acc[d0][8*m+1]);
      int pl1 = pack2(acc[d0][8*m+2], acc[d0][8*m+3]);
      int ph0 = pack2(acc[d0][8*m+4], acc[d0][8*m+5]);
      int ph1 = pack2(acc[d0][8*m+6], acc[d0][8*m+7]);
      int xl0 = __shfl_xor(pl0, 32);
      int xl1 = __shfl_xor(pl1, 32);
      int xh0 = __shfl_xor(ph0, 32);
      int xh1 = __shfl_xor(ph1, 32);
      i32x4 fr;
      fr[0] = hi ? xh0 : pl0;
      fr[1] = hi ? xh1 : pl1;
      fr[2] = hi ? ph0 : xl0;
      fr[3] = hi ? ph1 : xl1;
      bO[2*d0+m] = __builtin_bit_cast(half8, fr);
    }
  }

  f32x16 acc2[4];
  #pragma unroll
  for (int ob = 0; ob < 4; ob++)
    #pragma unroll
    for (int i = 0; i < 16; i++) acc2[ob][i] = 0.f;
  #pragma unroll
  for (int ks = 0; ks < 8; ks++){
    #pragma unroll
    for (int ob = 0; ob < 4; ob++){
      half8 af = *(const half8*)(woT + (size_t)(32*ob + q31)*DD + 16*ks + 8*hi);
      acc2[ob] = __builtin_amdgcn_mfma_f32_32x32x16_f16(af, bO[ks], acc2[ob], 0,0,0);
    }
  }

  // ---- epilogue: kur partial store, part[q][odim]; b64-packed ----
  f16* pb = part + (size_t)bid*(QTILE*DD) + (size_t)(32*w + q31)*DD;
  #pragma unroll
  for (int ob = 0; ob < 4; ob++){
    #pragma unroll
    for (int j = 0; j < 4; j++){
      i32x2 pw = { pack2(acc2[ob][4*j+0], acc2[ob][4*j+1]),
                   pack2(acc2[ob][4*j+2], acc2[ob][4*j+3]) };
      *(i32x2*)(pb + 32*ob + 8*j + 4*hi) = pw;
    }
  }
}

// ====== k_comb5 (512 threads / 8 waves, 32 rows/block): split-K sum of fp16 kur partials;
//        tot = mf + kur + bo; tangent proj; RK4; retract; fused next-stage q-proj ======
__global__ __launch_bounds__(512) void k_comb5(
    const float* __restrict__ z, const float* __restrict__ bo,
    const float* __restrict__ mf, const f16* __restrict__ part,
    const float* __restrict__ zin, float* __restrict__ zout,
    float* __restrict__ vsum, float* __restrict__ out,
    const float* __restrict__ Wq, const float* __restrict__ bq, f16* __restrict__ qhb,
    float wsum, float cretr, int first, int last)
{
  __shared__ f16 Wqh[DD*DD];     // 32 KB (Wq, staged only when !last)
  __shared__ float As[32*DD];    // 16 KB
  int tid = threadIdx.x;
  int r0 = blockIdx.x * 32;
  if (!last){
    #pragma unroll
    for (int it = 0; it < 4; it++){
      int idx = tid + it*512;               // 2048 half8 chunks
      f32x4 a = *(const f32x4*)(Wq + (size_t)idx*8);
      f32x4 b = *(const f32x4*)(Wq + (size_t)idx*8 + 4);
      half8 h;
      #pragma unroll
      for (int u = 0; u < 4; u++){ h[u] = (f16)a[u]; h[4+u] = (f16)b[u]; }
      *(half8*)(Wqh + (size_t)idx*8) = h;
    }
  }
  // ---- inline split-K reduction of fp16 kur partials into As (rows r0..r0+31) ----
  {
    int b = r0 >> 12;
    int t = r0 & 4095;
    int qt = t >> 7;
    int ro = t & 127;
    int nc = (2*qt + 5) >> 2;     // ceil((2qt+2)/4)
    int base = 0;                 // LPT reversed prefix: larger qt's chunks come first
    #pragma unroll 1
    for (int j = NQT3-1; j > qt; j--) base += (2*j + 5) >> 2;
    size_t sb = ((size_t)b*NCHUNK + base)*(QTILE*DD) + (size_t)ro*DD;
    // 512 half8 slots = 4096 elements (32 rows x 128 dims); one slot per thread
    const f16* s = part + sb + (size_t)tid*8;
    float a[8];
    {
      half8 v = *(const half8*)(s);
      #pragma unroll
      for (int u = 0; u < 8; u++) a[u] = (float)v[u];
    }
    for (int cc = 1; cc < nc; cc++){
      half8 v = *(const half8*)(s + (size_t)cc*(QTILE*DD));
      #pragma unroll
      for (int u = 0; u < 8; u++) a[u] += (float)v[u];
    }
    f32x4 o0v = {a[0],a[1],a[2],a[3]}, o1v = {a[4],a[5],a[6],a[7]};
    *(f32x4*)(As + (size_t)tid*8) = o0v;
    *(f32x4*)(As + (size_t)tid*8 + 4) = o1v;
  }
  __syncthreads();
  int c = tid & 15, rr = tid >> 4;    // 32 rows, 16 col-groups of 8
  float kur0[8];
  {
    f32x4 k0a = *(const f32x4*)(As + rr*DD + c*8);
    f32x4 k0b = *(const f32x4*)(As + rr*DD + c*8 + 4);
    #pragma unroll
    for (int u = 0; u < 4; u++){
      kur0[u] = k0a[u] + bo[c*8+u];
      kur0[4+u] = k0b[u] + bo[c*8+4+u];
    }
  }
  size_t o0 = (size_t)(r0+rr)*DD + c*8;
  float tot0[8], zi0[8];
  {
    f32x4 m0a = *(const f32x4*)(mf + o0), m0b = *(const f32x4*)(mf + o0 + 4);
    f32x4 z0a = *(const f32x4*)(zin + o0), z0b = *(const f32x4*)(zin + o0 + 4);
    #pragma unroll
    for (int u = 0; u < 4; u++){
      tot0[u] = m0a[u] + kur0[u]; tot0[4+u] = m0b[u] + kur0[4+u];
      zi0[u] = z0a[u]; zi0[4+u] = z0b[u];
    }
  }
  float p0 = 0.f;
  #pragma unroll
  for (int u = 0; u < 8; u++){ p0 = fmaf(tot0[u], zi0[u], p0); }
  #pragma unroll
  for (int m = 1; m < 16; m <<= 1){ p0 += __shfl_xor(p0, m, 16); }
  float ki0[8], vs0[8];
  #pragma unroll
  for (int u = 0; u < 8; u++){
    ki0[u] = tot0[u] - p0 * zi0[u];
  }
  if (first){
    #pragma unroll
    for (int u = 0; u < 8; u++){ vs0[u] = wsum*ki0[u]; }
  } else {
    f32x4 v0a = *(const f32x4*)(vsum + o0), v0b = *(const f32x4*)(vsum + o0 + 4);
    #pragma unroll
    for (int u = 0; u < 4; u++){
      vs0[u] = fmaf(wsum, ki0[u], v0a[u]); vs0[4+u] = fmaf(wsum, ki0[4+u], v0b[u]);
    }
  }
  if (!last){
    f32x4 va = {vs0[0],vs0[1],vs0[2],vs0[3]}, vb = {vs0[4],vs0[5],vs0[6],vs0[7]};
    *(f32x4*)(vsum + o0) = va; *(f32x4*)(vsum + o0 + 4) = vb;
  }
  float nz0[8];
  {
    f32x4 z0a = *(const f32x4*)(z + o0), z0b = *(const f32x4*)(z + o0 + 4);
    #pragma unroll
    for (int u = 0; u < 4; u++){
      float d0a = last ? vs0[u]*(1.f/6.f)   : cretr*ki0[u];
      float d0b = last ? vs0[4+u]*(1.f/6.f) : cretr*ki0[4+u];
      nz0[u] = z0a[u] + d0a; nz0[4+u] = z0b[u] + d0b;
    }
  }
  float n0 = 0.f;
  #pragma unroll
  for (int u = 0; u < 8; u++){ n0 = fmaf(nz0[u], nz0[u], n0); }
  #pragma unroll
  for (int m = 1; m < 16; m <<= 1){ n0 += __shfl_xor(n0, m, 16); }
  float i0 = 1.f / fmaxf(sqrtf(n0), 1e-8f);
  float* dst = last ? out : zout;
  f32x4 ra = {nz0[0]*i0, nz0[1]*i0, nz0[2]*i0, nz0[3]*i0};
  f32x4 rb = {nz0[4]*i0, nz0[5]*i0, nz0[6]*i0, nz0[7]*i0};
  *(f32x4*)(dst + o0) = ra; *(f32x4*)(dst + o0 + 4) = rb;

  // ---- fused q-projection for the NEXT stage: q_hat = normalize(zc @ Wq + bq) ----
  if (!last){
    __syncthreads();                      // all reads of As are done
    *(f32x4*)(As + rr*DD + c*8)     = ra;
    *(f32x4*)(As + rr*DD + c*8 + 4) = rb;
    __syncthreads();
    float q0[8];
    #pragma unroll
    for (int u = 0; u < 8; u++){ q0[u] = bq[c*8+u]; }
    const float* qr0 = As + rr*DD;
    #pragma unroll 4
    for (int i = 0; i < DD; i++){
      half8 wv = *(const half8*)(Wqh + i*DD + c*8);
      float a0 = qr0[i];
      #pragma unroll
      for (int u = 0; u < 8; u++){
        q0[u] = fmaf(a0, (float)wv[u], q0[u]);
      }
    }
    float s0 = 0.f;
    #pragma unroll
    for (int u = 0; u < 8; u++){ s0 = fmaf(q0[u], q0[u], s0); }
    #pragma unroll
    for (int m = 1; m < 16; m <<= 1){ s0 += __shfl_xor(s0, m, 16); }
    float qi0 = 1.f / fmaxf(sqrtf(s0), 1e-8f);
    half8 h0;
    #pragma unroll
    for (int u = 0; u < 8; u++){ h0[u] = (f16)(q0[u]*qi0); }
    *(half8*)(qhb + (size_t)(r0+rr)*DD + c*8) = h0;
  }
}

extern "C" void kernel_launch(void* const* d_in, const int* in_sizes, int n_in,
                              void* d_out, int out_size, void* d_ws, size_t ws_size,
                              hipStream_t stream) {
  const float* z  = (const float*)d_in[0];
  const float* ck = (const float*)d_in[1];
  const float* cb = (const float*)d_in[2];
  const float* Wq = (const float*)d_in[3];
  const float* bq = (const float*)d_in[4];
  const float* Wk = (const float*)d_in[5];
  const float* bk = (const float*)d_in[6];
  const float* Wo = (const float*)d_in[7];
  const float* bo = (const float*)d_in[8];
  float* out = (float*)d_out;

  float* mf   = (float*)d_ws;          // [B,T,D] f32
  float* zc   = mf   + NELT;
  float* vsum = zc   + NELT;
  f16*   khb  = (f16*)(vsum + NELT);   // fp16 [B,T,D]
  f16*   khT  = khb  + NELT;           // fp16 [B,D,T]
  f16*   qhb  = khT  + NELT;           // fp16 [B,T,D]
  f16*   part = qhb  + NELT;           // [BB*NCHUNK][128][128] fp16 kur partials (~17.8 MB)
  f16*   woT  = part + (size_t)BB*NCHUNK*QTILE*DD;   // fp16 WoT [128][128]

  k_prep<<<1025, 256, 0, stream>>>(z, Wk, bk, ck, cb, Wq, bq, Wo, khb, khT, qhb, mf, woT);

  const float wv[4] = {1.f, 2.f, 2.f, 1.f};
  const float cv[4] = {0.5f, 0.5f, 1.f, 0.f};
  for (int st = 0; st < 4; st++){
    const float* zcur = (st == 0) ? z : zc;
    k_attn20<<<BB*NCHUNK, 256, 0, stream>>>(qhb, khb, khT, woT, part);
    k_comb5 <<<NROW/32, 512, 0, stream>>>(z, bo, mf, part, zcur, zc, vsum, out,
                                          Wq, bq, qhb, wv[st], cv[st], st == 0, st == 3);
  }
}

// Round 11
// 273.354 us; speedup vs baseline: 1.0942x; 1.0942x over previous
//
#include <hip/hip_runtime.h>
#include <hip/hip_bf16.h>

#define BB 2
#define TT 4096
#define DD 128
#define KK 256
#define NROW (BB*TT)    // 8192 rows
#define NELT (NROW*DD)  // 1048576 elements per [B,T,D] buffer

typedef _Float16 f16;
typedef __attribute__((ext_vector_type(8))) f16 half8;
typedef __attribute__((ext_vector_type(2))) __fp16 fp16x2;
typedef __attribute__((ext_vector_type(4))) float f32x4;
typedef __attribute__((ext_vector_type(16))) float f32x16;
typedef __attribute__((ext_vector_type(2))) int i32x2;
typedef __attribute__((ext_vector_type(4))) int i32x4;

__device__ __forceinline__ int pack2(float a, float b){
  fp16x2 h = __builtin_amdgcn_cvt_pkrtz(a, b);
  return __builtin_bit_cast(int, h);
}

// ---- stage a 128x128 f32 weight matrix into LDS as fp16 (32 KB), 256 threads ----
__device__ __forceinline__ void stage_w_f16(int tid, const float* __restrict__ W, f16* Wh){
  #pragma unroll
  for (int it = 0; it < 8; it++){
    int idx = tid + it*256;               // 2048 half8 chunks
    f32x4 a = *(const f32x4*)(W + (size_t)idx*8);
    f32x4 b = *(const f32x4*)(W + (size_t)idx*8 + 4);
    half8 h;
    #pragma unroll
    for (int u = 0; u < 4; u++){ h[u] = (f16)a[u]; h[4+u] = (f16)b[u]; }
    *(half8*)(Wh + (size_t)idx*8) = h;
  }
}

// ---- shared helper: 32-row fp32 matvec (fp16 W in LDS) + normalize -> fp16 rows (+transpose)
__device__ __forceinline__ void proj_norm_rows(
    int tid, int r0,
    const float* __restrict__ src, const float* __restrict__ W, const float* __restrict__ bias,
    f16* __restrict__ dst, f16* __restrict__ dstT)
{
  __shared__ f16 Wh[DD*DD];      // 32 KB
  __shared__ float zs[32*DD];    // 16 KB
  stage_w_f16(tid, W, Wh);
  #pragma unroll
  for (int it = 0; it < 4; it++){
    int idx = tid + it*256;
    *(f32x4*)(zs + idx*4) = *(const f32x4*)(src + (size_t)r0*DD + idx*4);
  }
  __syncthreads();
  int c = tid & 15, rr = tid >> 4;
  float acc0[8], acc1[8];
  #pragma unroll
  for (int u = 0; u < 8; u++){ float bv = bias[c*8+u]; acc0[u] = bv; acc1[u] = bv; }
  const float* zr0 = zs + rr*DD;
  const float* zr1 = zs + (rr+16)*DD;
  #pragma unroll 4
  for (int i = 0; i < DD; i++){
    half8 wv = *(const half8*)(Wh + i*DD + c*8);
    float a0 = zr0[i], a1 = zr1[i];
    #pragma unroll
    for (int u = 0; u < 8; u++){
      float w = (float)wv[u];
      acc0[u] = fmaf(a0, w, acc0[u]);
      acc1[u] = fmaf(a1, w, acc1[u]);
    }
  }
  float s0 = 0.f, s1 = 0.f;
  #pragma unroll
  for (int u = 0; u < 8; u++){ s0 = fmaf(acc0[u], acc0[u], s0); s1 = fmaf(acc1[u], acc1[u], s1); }
  #pragma unroll
  for (int m = 1; m < 16; m <<= 1){ s0 += __shfl_xor(s0, m, 16); s1 += __shfl_xor(s1, m, 16); }
  float inv0 = 1.f / fmaxf(sqrtf(s0), 1e-8f);
  float inv1 = 1.f / fmaxf(sqrtf(s1), 1e-8f);
  half8 h0, h1;
  #pragma unroll
  for (int u = 0; u < 8; u++){ h0[u] = (f16)(acc0[u]*inv0); h1[u] = (f16)(acc1[u]*inv1); }
  int row0 = r0 + rr, row1 = row0 + 16;
  *(half8*)(dst + (size_t)row0*DD + c*8) = h0;
  *(half8*)(dst + (size_t)row1*DD + c*8) = h1;
  if (dstT){
    int b = row0 >> 12, t0 = row0 & 4095, t1 = row1 & 4095;
    #pragma unroll
    for (int u = 0; u < 8; u++){
      dstT[((size_t)b*DD + c*8 + u)*TT + t0] = h0[u];
      dstT[((size_t)b*DD + c*8 + u)*TT + t1] = h1[u];
    }
  }
}

// ======== k_prep: blocks 0..511: conv; 512..767: k-proj; 768..1023: q0-proj; 1024: WoT ==
__global__ __launch_bounds__(256) void k_prep(
    const float* __restrict__ z, const float* __restrict__ Wk, const float* __restrict__ bk,
    const float* __restrict__ ck, const float* __restrict__ cb,
    const float* __restrict__ Wq, const float* __restrict__ bq,
    const float* __restrict__ Wo,
    f16* __restrict__ khb, f16* __restrict__ khT, f16* __restrict__ qhb,
    float* __restrict__ mf, f16* __restrict__ woT)
{
  int tid = threadIdx.x;
  if (blockIdx.x < 512){
    int bid = blockIdx.x;
    int d = tid & 127, tg = tid >> 7;
    int b = bid >> 8;
    int tbase = ((bid & 255) << 4) + tg*8;
    const float* zb = z + (size_t)b*TT*DD;
    float acc[8];
    #pragma unroll
    for (int j = 0; j < 8; j++) acc[j] = 0.f;
    float ckq[8];
    #pragma unroll
    for (int u = 0; u < 8; u++) ckq[u] = 0.f;
    int sstart = tbase - (KK-1);
    for (int ch = 0; ch < 33; ch++){
      #pragma unroll
      for (int u = 0; u < 8; u++){
        int base = ch*8 + u;
        int s = sstart + base;
        float zv = ((unsigned)s < (unsigned)TT && base < 263) ? zb[(size_t)s*DD + d] : 0.f;
        ckq[u] = (base < KK) ? ck[(size_t)base*DD + d] : 0.f;
        #pragma unroll
        for (int j = 0; j < 8; j++) acc[j] = fmaf(ckq[(u-j)&7], zv, acc[j]);
      }
    }
    float cbv = cb[d];
    #pragma unroll
    for (int j = 0; j < 8; j++)
      mf[((size_t)b*TT + tbase + j)*DD + d] = acc[j] + cbv;
  } else if (blockIdx.x < 768){
    proj_norm_rows(tid, (blockIdx.x - 512) * 32, z, Wk, bk, khb, khT);
  } else if (blockIdx.x < 1024){
    proj_norm_rows(tid, (blockIdx.x - 768) * 32, z, Wq, bq, qhb, nullptr);
  } else {
    // ---- one-shot WoT fp16: woT[odim j][idim i] = Wo[i][j] ----
    int j  = tid >> 1;          // 0..127
    int ib = tid & 1;           // 0/1
    #pragma unroll
    for (int u = 0; u < 8; u++){
      int i0 = ib*64 + u*8;
      half8 h;
      #pragma unroll
      for (int k = 0; k < 8; k++) h[k] = (f16)Wo[(size_t)(i0+k)*DD + j];
      *(half8*)(woT + (size_t)j*DD + i0) = h;
    }
  }
}

// ====== MFMA attention v21: R9 structure (CH=8), Wo epilogue from precomputed global WoT ==
#define QTILE 128
#define NQT3 (TT/QTILE)     // 32 q-tiles per batch
#define NCHUNK 144          // sum_{qt=0}^{31} ceil((qt+1)/4), chunks of 8 key-tiles

__global__ __launch_bounds__(256,2) void k_attn21(
    const f16* __restrict__ qhb, const f16* __restrict__ khb,
    const f16* __restrict__ khT, const f16* __restrict__ woT,
    f16* __restrict__ part)
{
  int bid = blockIdx.x;
  int b = bid / NCHUNK;
  int rem = bid - b*NCHUNK;
  int qt = 0, chunk = 0;
  #pragma unroll 1
  for (int j = NQT3-1; j >= 0; j--){
    int nch = (j + 4) >> 2;     // ceil((j+1)/4)
    if (rem < nch){ qt = j; chunk = rem; break; }
    rem -= nch;
  }
  int kt0 = chunk * 8;
  int kt1 = min(kt0 + 7, 2*qt + 1);
  int t0 = qt * QTILE;

  __shared__ __align__(16) f16 KbD[2][64*136];   // [key][dim], stride 136
  __shared__ __align__(16) f16 KtD[2][128*72];   // [dim][key], stride 72

  int tid  = threadIdx.x;
  int w    = tid >> 6;        // 4 waves, wave w owns q-rows 32w..32w+31
  int lane = tid & 63;
  int q31  = lane & 31;
  int hi   = lane >> 5;

  const f16* qg  = qhb + (size_t)b*TT*DD;
  const f16* kg  = khb + (size_t)b*TT*DD;
  const f16* ktg = khT + (size_t)b*DD*TT;

  int sb_r  = tid >> 4, sb_c = (tid & 15)*8;   // Kb staging
  int st_r  = tid >> 3, st_c = (tid & 7)*8;    // Kt staging

  int qrow_g = t0 + 32*w + q31;

  // Q fragments (B-operand): lane holds Q[qrow_g][16ks + 8hi + 0..7]
  half8 qb[8];
  {
    const f16* qrow = qg + (size_t)qrow_g*DD + 8*hi;
    #pragma unroll
    for (int ks = 0; ks < 8; ks++) qb[ks] = *(const half8*)(qrow + 16*ks);
  }

  // acc = O^T: acc[d0][r] = O^T[dim=32d0+(r&3)+8(r>>2)+4hi][q=q31]
  f32x16 acc[4];
  #pragma unroll
  for (int d = 0; d < 4; d++)
    #pragma unroll
    for (int i = 0; i < 16; i++) acc[d][i] = 0.f;

  // ---- prologue: stage first tile ----
  half8 sKb[4], sKt[4];
  {
    int s0 = kt0 * 64;
    #pragma unroll
    for (int it = 0; it < 4; it++)
      sKb[it] = *(const half8*)(kg + (size_t)(s0 + sb_r + it*16)*DD + sb_c);
    #pragma unroll
    for (int it = 0; it < 4; it++)
      sKt[it] = *(const half8*)(ktg + (size_t)(st_r + it*32)*TT + s0 + st_c);
    #pragma unroll
    for (int it = 0; it < 4; it++)
      *(half8*)(&KbD[0][0] + (sb_r + it*16)*136 + sb_c) = sKb[it];
    #pragma unroll
    for (int it = 0; it < 4; it++)
      *(half8*)(&KtD[0][0] + (st_r + it*32)*72 + st_c) = sKt[it];
  }
  __syncthreads();

  #pragma unroll 1
  for (int kt = kt0; kt <= kt1; kt++){
    int cur = (kt - kt0) & 1;
    const f16* KbL = &KbD[cur][0];
    const f16* KtL = &KtD[cur][0];

    // issue next tile's global loads first (latency hides under compute)
    if (kt < kt1){
      int s0n = (kt+1) * 64;
      #pragma unroll
      for (int it = 0; it < 4; it++)
        sKb[it] = *(const half8*)(kg + (size_t)(s0n + sb_r + it*16)*DD + sb_c);
      #pragma unroll
      for (int it = 0; it < 4; it++)
        sKt[it] = *(const half8*)(ktg + (size_t)(st_r + it*32)*TT + s0n + st_c);
    }

    int s0 = kt * 64;
    // ---- QK^T: A = K rows (LDS b128), B = Q regs -> S^T[key32][q32] x2 ----
    f32x16 sa0, sa1;
    #pragma unroll
    for (int i = 0; i < 16; i++){ sa0[i] = 0.f; sa1[i] = 0.f; }
    #pragma unroll
    for (int ks = 0; ks < 8; ks++){
      half8 a0 = *(const half8*)(KbL + (q31)      *136 + 16*ks + 8*hi);
      half8 a1 = *(const half8*)(KbL + (32 + q31) *136 + 16*ks + 8*hi);
      sa0 = __builtin_amdgcn_mfma_f32_32x32x16_f16(a0, qb[ks], sa0, 0,0,0);
      sa1 = __builtin_amdgcn_mfma_f32_32x32x16_f16(a1, qb[ks], sa1, 0,0,0);
    }

    // ---- sin + causal mask, in-register ----
    float p0v[16], p1v[16];
    #pragma unroll
    for (int r = 0; r < 16; r++){
      int kr = (r&3) + 8*(r>>2) + 4*hi;
      p0v[r] = (s0 + kr      <= qrow_g) ? __sinf(sa0[r]) : 0.f;
      p1v[r] = (s0 + 32 + kr <= qrow_g) ? __sinf(sa1[r]) : 0.f;
    }

    // ---- in-register P regroup (cvt_pk + shfl_xor(32)) ----
    half8 pf[4];
    #pragma unroll
    for (int kb = 0; kb < 2; kb++){
      const float* pv = kb ? p1v : p0v;
      #pragma unroll
      for (int u = 0; u < 2; u++){
        int pl0 = pack2(pv[8*u+0], pv[8*u+1]);
        int pl1 = pack2(pv[8*u+2], pv[8*u+3]);
        int ph0 = pack2(pv[8*u+4], pv[8*u+5]);
        int ph1 = pack2(pv[8*u+6], pv[8*u+7]);
        int xl0 = __shfl_xor(pl0, 32);
        int xl1 = __shfl_xor(pl1, 32);
        int xh0 = __shfl_xor(ph0, 32);
        int xh1 = __shfl_xor(ph1, 32);
        i32x4 fr;
        fr[0] = hi ? xh0 : pl0;
        fr[1] = hi ? xh1 : pl1;
        fr[2] = hi ? ph0 : xl0;
        fr[3] = hi ? ph1 : xl1;
        pf[2*kb+u] = __builtin_bit_cast(half8, fr);
      }
    }

    // ---- PV swapped: A = Kt rows, B = P frags -> O^T[dim32][q32] x4 ----
    #pragma unroll
    for (int s = 0; s < 4; s++){
      #pragma unroll
      for (int d0 = 0; d0 < 4; d0++){
        half8 bf = *(const half8*)(KtL + (32*d0 + q31)*72 + 16*s + 8*hi);
        acc[d0] = __builtin_amdgcn_mfma_f32_32x32x16_f16(bf, pf[s], acc[d0], 0,0,0);
      }
    }

    // ---- write next tile into the other LDS buffer; single barrier per tile ----
    if (kt < kt1){
      f16* KbN = &KbD[cur^1][0];
      f16* KtN = &KtD[cur^1][0];
      #pragma unroll
      for (int it = 0; it < 4; it++)
        *(half8*)(KbN + (sb_r + it*16)*136 + sb_c) = sKb[it];
      #pragma unroll
      for (int it = 0; it < 4; it++)
        *(half8*)(KtN + (st_r + it*32)*72 + st_c) = sKt[it];
      __syncthreads();
    }
  }

  // ====== fused Wo projection: kur^T = Wo^T @ O^T; WoT frags direct from global (L2) ======
  // no barriers needed: no LDS involved in the epilogue
  half8 bO[8];
  #pragma unroll
  for (int d0 = 0; d0 < 4; d0++){
    #pragma unroll
    for (int m = 0; m < 2; m++){
      int pl0 = pack2(acc[d0][8*m+0], acc[d0][8*m+1]);
      int pl1 = pack2(acc[d0][8*m+2], acc[d0][8*m+3]);
      int ph0 = pack2(acc[d0][8*m+4], acc[d0][8*m+5]);
      int ph1 = pack2(acc[d0][8*m+6], acc[d0][8*m+7]);
      int xl0 = __shfl_xor(pl0, 32);
      int xl1 = __shfl_xor(pl1, 32);
      int xh0 = __shfl_xor(ph0, 32);
      int xh1 = __shfl_xor(ph1, 32);
      i32x4 fr;
      fr[0] = hi ? xh0 : pl0;
      fr[1] = hi ? xh1 : pl1;
      fr[2] = hi ? ph0 : xl0;
      fr[3] = hi ? ph1 : xl1;
      bO[2*d0+m] = __builtin_bit_cast(half8, fr);
    }
  }

  f32x16 acc2[4];
  #pragma unroll
  for (int ob = 0; ob < 4; ob++)
    #pragma unroll
    for (int i = 0; i < 16; i++) acc2[ob][i] = 0.f;
  #pragma unroll
  for (int ks = 0; ks < 8; ks++){
    #pragma unroll
    for (int ob = 0; ob < 4; ob++){
      half8 af = *(const half8*)(woT + (size_t)(32*ob + q31)*DD + 16*ks + 8*hi);
      acc2[ob] = __builtin_amdgcn_mfma_f32_32x32x16_f16(af, bO[ks], acc2[ob], 0,0,0);
    }
  }

  // ---- epilogue: kur partial store, part[q][odim]; b64-packed ----
  f16* pb = part + (size_t)bid*(QTILE*DD) + (size_t)(32*w + q31)*DD;
  #pragma unroll
  for (int ob = 0; ob < 4; ob++){
    #pragma unroll
    for (int j = 0; j < 4; j++){
      i32x2 pw = { pack2(acc2[ob][4*j+0], acc2[ob][4*j+1]),
                   pack2(acc2[ob][4*j+2], acc2[ob][4*j+3]) };
      *(i32x2*)(pb + 32*ob + 8*j + 4*hi) = pw;
    }
  }
}

// ====== k_comb5 (512 threads / 8 waves, 32 rows/block): split-K sum of fp16 kur partials;
//        tot = mf + kur + bo; tangent proj; RK4; retract; fused next-stage q-proj ======
__global__ __launch_bounds__(512) void k_comb5(
    const float* __restrict__ z, const float* __restrict__ bo,
    const float* __restrict__ mf, const f16* __restrict__ part,
    const float* __restrict__ zin, float* __restrict__ zout,
    float* __restrict__ vsum, float* __restrict__ out,
    const float* __restrict__ Wq, const float* __restrict__ bq, f16* __restrict__ qhb,
    float wsum, float cretr, int first, int last)
{
  __shared__ f16 Wqh[DD*DD];     // 32 KB (Wq, staged only when !last)
  __shared__ float As[32*DD];    // 16 KB
  int tid = threadIdx.x;
  int r0 = blockIdx.x * 32;
  if (!last){
    #pragma unroll
    for (int it = 0; it < 4; it++){
      int idx = tid + it*512;               // 2048 half8 chunks
      f32x4 a = *(const f32x4*)(Wq + (size_t)idx*8);
      f32x4 b = *(const f32x4*)(Wq + (size_t)idx*8 + 4);
      half8 h;
      #pragma unroll
      for (int u = 0; u < 4; u++){ h[u] = (f16)a[u]; h[4+u] = (f16)b[u]; }
      *(half8*)(Wqh + (size_t)idx*8) = h;
    }
  }
  // ---- inline split-K reduction of fp16 kur partials into As (rows r0..r0+31) ----
  {
    int b = r0 >> 12;
    int t = r0 & 4095;
    int qt = t >> 7;
    int ro = t & 127;
    int nc = (qt + 4) >> 2;       // ceil((qt+1)/4)
    int base = 0;                 // LPT reversed prefix: larger qt's chunks come first
    #pragma unroll 1
    for (int j = NQT3-1; j > qt; j--) base += (j + 4) >> 2;
    size_t sb = ((size_t)b*NCHUNK + base)*(QTILE*DD) + (size_t)ro*DD;
    // 512 half8 slots = 4096 elements (32 rows x 128 dims); one slot per thread
    const f16* s = part + sb + (size_t)tid*8;
    float a[8];
    {
      half8 v = *(const half8*)(s);
      #pragma unroll
      for (int u = 0; u < 8; u++) a[u] = (float)v[u];
    }
    for (int cc = 1; cc < nc; cc++){
      half8 v = *(const half8*)(s + (size_t)cc*(QTILE*DD));
      #pragma unroll
      for (int u = 0; u < 8; u++) a[u] += (float)v[u];
    }
    f32x4 o0v = {a[0],a[1],a[2],a[3]}, o1v = {a[4],a[5],a[6],a[7]};
    *(f32x4*)(As + (size_t)tid*8) = o0v;
    *(f32x4*)(As + (size_t)tid*8 + 4) = o1v;
  }
  __syncthreads();
  int c = tid & 15, rr = tid >> 4;    // 32 rows, 16 col-groups of 8
  float kur0[8];
  {
    f32x4 k0a = *(const f32x4*)(As + rr*DD + c*8);
    f32x4 k0b = *(const f32x4*)(As + rr*DD + c*8 + 4);
    #pragma unroll
    for (int u = 0; u < 4; u++){
      kur0[u] = k0a[u] + bo[c*8+u];
      kur0[4+u] = k0b[u] + bo[c*8+4+u];
    }
  }
  size_t o0 = (size_t)(r0+rr)*DD + c*8;
  float tot0[8], zi0[8];
  {
    f32x4 m0a = *(const f32x4*)(mf + o0), m0b = *(const f32x4*)(mf + o0 + 4);
    f32x4 z0a = *(const f32x4*)(zin + o0), z0b = *(const f32x4*)(zin + o0 + 4);
    #pragma unroll
    for (int u = 0; u < 4; u++){
      tot0[u] = m0a[u] + kur0[u]; tot0[4+u] = m0b[u] + kur0[4+u];
      zi0[u] = z0a[u]; zi0[4+u] = z0b[u];
    }
  }
  float p0 = 0.f;
  #pragma unroll
  for (int u = 0; u < 8; u++){ p0 = fmaf(tot0[u], zi0[u], p0); }
  #pragma unroll
  for (int m = 1; m < 16; m <<= 1){ p0 += __shfl_xor(p0, m, 16); }
  float ki0[8], vs0[8];
  #pragma unroll
  for (int u = 0; u < 8; u++){
    ki0[u] = tot0[u] - p0 * zi0[u];
  }
  if (first){
    #pragma unroll
    for (int u = 0; u < 8; u++){ vs0[u] = wsum*ki0[u]; }
  } else {
    f32x4 v0a = *(const f32x4*)(vsum + o0), v0b = *(const f32x4*)(vsum + o0 + 4);
    #pragma unroll
    for (int u = 0; u < 4; u++){
      vs0[u] = fmaf(wsum, ki0[u], v0a[u]); vs0[4+u] = fmaf(wsum, ki0[4+u], v0b[u]);
    }
  }
  if (!last){
    f32x4 va = {vs0[0],vs0[1],vs0[2],vs0[3]}, vb = {vs0[4],vs0[5],vs0[6],vs0[7]};
    *(f32x4*)(vsum + o0) = va; *(f32x4*)(vsum + o0 + 4) = vb;
  }
  float nz0[8];
  {
    f32x4 z0a = *(const f32x4*)(z + o0), z0b = *(const f32x4*)(z + o0 + 4);
    #pragma unroll
    for (int u = 0; u < 4; u++){
      float d0a = last ? vs0[u]*(1.f/6.f)   : cretr*ki0[u];
      float d0b = last ? vs0[4+u]*(1.f/6.f) : cretr*ki0[4+u];
      nz0[u] = z0a[u] + d0a; nz0[4+u] = z0b[u] + d0b;
    }
  }
  float n0 = 0.f;
  #pragma unroll
  for (int u = 0; u < 8; u++){ n0 = fmaf(nz0[u], nz0[u], n0); }
  #pragma unroll
  for (int m = 1; m < 16; m <<= 1){ n0 += __shfl_xor(n0, m, 16); }
  float i0 = 1.f / fmaxf(sqrtf(n0), 1e-8f);
  float* dst = last ? out : zout;
  f32x4 ra = {nz0[0]*i0, nz0[1]*i0, nz0[2]*i0, nz0[3]*i0};
  f32x4 rb = {nz0[4]*i0, nz0[5]*i0, nz0[6]*i0, nz0[7]*i0};
  *(f32x4*)(dst + o0) = ra; *(f32x4*)(dst + o0 + 4) = rb;

  // ---- fused q-projection for the NEXT stage: q_hat = normalize(zc @ Wq + bq) ----
  if (!last){
    __syncthreads();                      // all reads of As are done
    *(f32x4*)(As + rr*DD + c*8)     = ra;
    *(f32x4*)(As + rr*DD + c*8 + 4) = rb;
    __syncthreads();
    float q0[8];
    #pragma unroll
    for (int u = 0; u < 8; u++){ q0[u] = bq[c*8+u]; }
    const float* qr0 = As + rr*DD;
    #pragma unroll 4
    for (int i = 0; i < DD; i++){
      half8 wv = *(const half8*)(Wqh + i*DD + c*8);
      float a0 = qr0[i];
      #pragma unroll
      for (int u = 0; u < 8; u++){
        q0[u] = fmaf(a0, (float)wv[u], q0[u]);
      }
    }
    float s0 = 0.f;
    #pragma unroll
    for (int u = 0; u < 8; u++){ s0 = fmaf(q0[u], q0[u], s0); }
    #pragma unroll
    for (int m = 1; m < 16; m <<= 1){ s0 += __shfl_xor(s0, m, 16); }
    float qi0 = 1.f / fmaxf(sqrtf(s0), 1e-8f);
    half8 h0;
    #pragma unroll
    for (int u = 0; u < 8; u++){ h0[u] = (f16)(q0[u]*qi0); }
    *(half8*)(qhb + (size_t)(r0+rr)*DD + c*8) = h0;
  }
}

extern "C" void kernel_launch(void* const* d_in, const int* in_sizes, int n_in,
                              void* d_out, int out_size, void* d_ws, size_t ws_size,
                              hipStream_t stream) {
  const float* z  = (const float*)d_in[0];
  const float* ck = (const float*)d_in[1];
  const float* cb = (const float*)d_in[2];
  const float* Wq = (const float*)d_in[3];
  const float* bq = (const float*)d_in[4];
  const float* Wk = (const float*)d_in[5];
  const float* bk = (const float*)d_in[6];
  const float* Wo = (const float*)d_in[7];
  const float* bo = (const float*)d_in[8];
  float* out = (float*)d_out;

  float* mf   = (float*)d_ws;          // [B,T,D] f32
  float* zc   = mf   + NELT;
  float* vsum = zc   + NELT;
  f16*   khb  = (f16*)(vsum + NELT);   // fp16 [B,T,D]
  f16*   khT  = khb  + NELT;           // fp16 [B,D,T]
  f16*   qhb  = khT  + NELT;           // fp16 [B,T,D]
  f16*   part = qhb  + NELT;           // [BB*NCHUNK][128][128] fp16 kur partials (~9.4 MB)
  f16*   woT  = part + (size_t)BB*NCHUNK*QTILE*DD;   // fp16 WoT [128][128]

  k_prep<<<1025, 256, 0, stream>>>(z, Wk, bk, ck, cb, Wq, bq, Wo, khb, khT, qhb, mf, woT);

  const float wv[4] = {1.f, 2.f, 2.f, 1.f};
  const float cv[4] = {0.5f, 0.5f, 1.f, 0.f};
  for (int st = 0; st < 4; st++){
    const float* zcur = (st == 0) ? z : zc;
    k_attn21<<<BB*NCHUNK, 256, 0, stream>>>(qhb, khb, khT, woT, part);
    k_comb5 <<<NROW/32, 512, 0, stream>>>(z, bo, mf, part, zcur, zc, vsum, out,
                                          Wq, bq, qhb, wv[st], cv[st], st == 0, st == 3);
  }
}

// Round 12
// 261.135 us; speedup vs baseline: 1.1454x; 1.0468x over previous
//
#include <hip/hip_runtime.h>
#include <hip/hip_bf16.h>

#define BB 2
#define TT 4096
#define DD 128
#define KK 256
#define NROW (BB*TT)    // 8192 rows
#define NELT (NROW*DD)  // 1048576 elements per [B,T,D] buffer

typedef _Float16 f16;
typedef __attribute__((ext_vector_type(8))) f16 half8;
typedef __attribute__((ext_vector_type(2))) __fp16 fp16x2;
typedef __attribute__((ext_vector_type(4))) float f32x4;
typedef __attribute__((ext_vector_type(16))) float f32x16;
typedef __attribute__((ext_vector_type(2))) int i32x2;
typedef __attribute__((ext_vector_type(4))) int i32x4;

__device__ __forceinline__ int pack2(float a, float b){
  fp16x2 h = __builtin_amdgcn_cvt_pkrtz(a, b);
  return __builtin_bit_cast(int, h);
}

// ---- stage a 128x128 f32 weight matrix into LDS as fp16 (32 KB), 256 threads ----
__device__ __forceinline__ void stage_w_f16(int tid, const float* __restrict__ W, f16* Wh){
  #pragma unroll
  for (int it = 0; it < 8; it++){
    int idx = tid + it*256;               // 2048 half8 chunks
    f32x4 a = *(const f32x4*)(W + (size_t)idx*8);
    f32x4 b = *(const f32x4*)(W + (size_t)idx*8 + 4);
    half8 h;
    #pragma unroll
    for (int u = 0; u < 4; u++){ h[u] = (f16)a[u]; h[4+u] = (f16)b[u]; }
    *(half8*)(Wh + (size_t)idx*8) = h;
  }
}

// ---- shared helper: 32-row fp32 matvec (fp16 W in LDS) + normalize -> fp16 rows (+transpose)
__device__ __forceinline__ void proj_norm_rows(
    int tid, int r0,
    const float* __restrict__ src, const float* __restrict__ W, const float* __restrict__ bias,
    f16* __restrict__ dst, f16* __restrict__ dstT)
{
  __shared__ f16 Wh[DD*DD];      // 32 KB
  __shared__ float zs[32*DD];    // 16 KB
  stage_w_f16(tid, W, Wh);
  #pragma unroll
  for (int it = 0; it < 4; it++){
    int idx = tid + it*256;
    *(f32x4*)(zs + idx*4) = *(const f32x4*)(src + (size_t)r0*DD + idx*4);
  }
  __syncthreads();
  int c = tid & 15, rr = tid >> 4;
  float acc0[8], acc1[8];
  #pragma unroll
  for (int u = 0; u < 8; u++){ float bv = bias[c*8+u]; acc0[u] = bv; acc1[u] = bv; }
  const float* zr0 = zs + rr*DD;
  const float* zr1 = zs + (rr+16)*DD;
  #pragma unroll 4
  for (int i = 0; i < DD; i++){
    half8 wv = *(const half8*)(Wh + i*DD + c*8);
    float a0 = zr0[i], a1 = zr1[i];
    #pragma unroll
    for (int u = 0; u < 8; u++){
      float w = (float)wv[u];
      acc0[u] = fmaf(a0, w, acc0[u]);
      acc1[u] = fmaf(a1, w, acc1[u]);
    }
  }
  float s0 = 0.f, s1 = 0.f;
  #pragma unroll
  for (int u = 0; u < 8; u++){ s0 = fmaf(acc0[u], acc0[u], s0); s1 = fmaf(acc1[u], acc1[u], s1); }
  #pragma unroll
  for (int m = 1; m < 16; m <<= 1){ s0 += __shfl_xor(s0, m, 16); s1 += __shfl_xor(s1, m, 16); }
  float inv0 = 1.f / fmaxf(sqrtf(s0), 1e-8f);
  float inv1 = 1.f / fmaxf(sqrtf(s1), 1e-8f);
  half8 h0, h1;
  #pragma unroll
  for (int u = 0; u < 8; u++){ h0[u] = (f16)(acc0[u]*inv0); h1[u] = (f16)(acc1[u]*inv1); }
  int row0 = r0 + rr, row1 = row0 + 16;
  *(half8*)(dst + (size_t)row0*DD + c*8) = h0;
  *(half8*)(dst + (size_t)row1*DD + c*8) = h1;
  if (dstT){
    int b = row0 >> 12, t0 = row0 & 4095, t1 = row1 & 4095;
    #pragma unroll
    for (int u = 0; u < 8; u++){
      dstT[((size_t)b*DD + c*8 + u)*TT + t0] = h0[u];
      dstT[((size_t)b*DD + c*8 + u)*TT + t1] = h1[u];
    }
  }
}

// ======== k_prep: blocks 0..511: conv; 512..767: k-proj; 768..1023: q0-proj; 1024: WoT ==
__global__ __launch_bounds__(256) void k_prep(
    const float* __restrict__ z, const float* __restrict__ Wk, const float* __restrict__ bk,
    const float* __restrict__ ck, const float* __restrict__ cb,
    const float* __restrict__ Wq, const float* __restrict__ bq,
    const float* __restrict__ Wo,
    f16* __restrict__ khb, f16* __restrict__ khT, f16* __restrict__ qhb,
    float* __restrict__ mf, f16* __restrict__ woT)
{
  int tid = threadIdx.x;
  if (blockIdx.x < 512){
    int bid = blockIdx.x;
    int d = tid & 127, tg = tid >> 7;
    int b = bid >> 8;
    int tbase = ((bid & 255) << 4) + tg*8;
    const float* zb = z + (size_t)b*TT*DD;
    float acc[8];
    #pragma unroll
    for (int j = 0; j < 8; j++) acc[j] = 0.f;
    float ckq[8];
    #pragma unroll
    for (int u = 0; u < 8; u++) ckq[u] = 0.f;
    int sstart = tbase - (KK-1);
    for (int ch = 0; ch < 33; ch++){
      #pragma unroll
      for (int u = 0; u < 8; u++){
        int base = ch*8 + u;
        int s = sstart + base;
        float zv = ((unsigned)s < (unsigned)TT && base < 263) ? zb[(size_t)s*DD + d] : 0.f;
        ckq[u] = (base < KK) ? ck[(size_t)base*DD + d] : 0.f;
        #pragma unroll
        for (int j = 0; j < 8; j++) acc[j] = fmaf(ckq[(u-j)&7], zv, acc[j]);
      }
    }
    float cbv = cb[d];
    #pragma unroll
    for (int j = 0; j < 8; j++)
      mf[((size_t)b*TT + tbase + j)*DD + d] = acc[j] + cbv;
  } else if (blockIdx.x < 768){
    proj_norm_rows(tid, (blockIdx.x - 512) * 32, z, Wk, bk, khb, khT);
  } else if (blockIdx.x < 1024){
    proj_norm_rows(tid, (blockIdx.x - 768) * 32, z, Wq, bq, qhb, nullptr);
  } else {
    // ---- one-shot WoT fp16: woT[odim j][idim i] = Wo[i][j] ----
    int j  = tid >> 1;          // 0..127
    int ib = tid & 1;           // 0/1
    #pragma unroll
    for (int u = 0; u < 8; u++){
      int i0 = ib*64 + u*8;
      half8 h;
      #pragma unroll
      for (int k = 0; k < 8; k++) h[k] = (f16)Wo[(size_t)(i0+k)*DD + j];
      *(half8*)(woT + (size_t)j*DD + i0) = h;
    }
  }
}

// ====== MFMA attention v22: R9 structure (CH=8); Wo epilogue = coalesced woT->LDS stage
//        + LDS MFMA reads (best of R9/R11 epilogues) ======
#define QTILE 128
#define NQT3 (TT/QTILE)     // 32 q-tiles per batch
#define NCHUNK 144          // sum_{qt=0}^{31} ceil((qt+1)/4), chunks of 8 key-tiles

__global__ __launch_bounds__(256,2) void k_attn22(
    const f16* __restrict__ qhb, const f16* __restrict__ khb,
    const f16* __restrict__ khT, const f16* __restrict__ woT,
    f16* __restrict__ part)
{
  int bid = blockIdx.x;
  int b = bid / NCHUNK;
  int rem = bid - b*NCHUNK;
  int qt = 0, chunk = 0;
  #pragma unroll 1
  for (int j = NQT3-1; j >= 0; j--){
    int nch = (j + 4) >> 2;     // ceil((j+1)/4)
    if (rem < nch){ qt = j; chunk = rem; break; }
    rem -= nch;
  }
  int kt0 = chunk * 8;
  int kt1 = min(kt0 + 7, 2*qt + 1);
  int t0 = qt * QTILE;

  __shared__ __align__(16) f16 KbD[2][64*136];   // [key][dim], stride 136; reused as WoT LDS
  __shared__ __align__(16) f16 KtD[2][128*72];   // [dim][key], stride 72

  int tid  = threadIdx.x;
  int w    = tid >> 6;        // 4 waves, wave w owns q-rows 32w..32w+31
  int lane = tid & 63;
  int q31  = lane & 31;
  int hi   = lane >> 5;

  const f16* qg  = qhb + (size_t)b*TT*DD;
  const f16* kg  = khb + (size_t)b*TT*DD;
  const f16* ktg = khT + (size_t)b*DD*TT;

  int sb_r  = tid >> 4, sb_c = (tid & 15)*8;   // Kb staging
  int st_r  = tid >> 3, st_c = (tid & 7)*8;    // Kt staging

  int qrow_g = t0 + 32*w + q31;

  // Q fragments (B-operand): lane holds Q[qrow_g][16ks + 8hi + 0..7]
  half8 qb[8];
  {
    const f16* qrow = qg + (size_t)qrow_g*DD + 8*hi;
    #pragma unroll
    for (int ks = 0; ks < 8; ks++) qb[ks] = *(const half8*)(qrow + 16*ks);
  }

  // acc = O^T: acc[d0][r] = O^T[dim=32d0+(r&3)+8(r>>2)+4hi][q=q31]
  f32x16 acc[4];
  #pragma unroll
  for (int d = 0; d < 4; d++)
    #pragma unroll
    for (int i = 0; i < 16; i++) acc[d][i] = 0.f;

  // ---- prologue: stage first tile ----
  half8 sKb[4], sKt[4];
  {
    int s0 = kt0 * 64;
    #pragma unroll
    for (int it = 0; it < 4; it++)
      sKb[it] = *(const half8*)(kg + (size_t)(s0 + sb_r + it*16)*DD + sb_c);
    #pragma unroll
    for (int it = 0; it < 4; it++)
      sKt[it] = *(const half8*)(ktg + (size_t)(st_r + it*32)*TT + s0 + st_c);
    #pragma unroll
    for (int it = 0; it < 4; it++)
      *(half8*)(&KbD[0][0] + (sb_r + it*16)*136 + sb_c) = sKb[it];
    #pragma unroll
    for (int it = 0; it < 4; it++)
      *(half8*)(&KtD[0][0] + (st_r + it*32)*72 + st_c) = sKt[it];
  }
  __syncthreads();

  #pragma unroll 1
  for (int kt = kt0; kt <= kt1; kt++){
    int cur = (kt - kt0) & 1;
    const f16* KbL = &KbD[cur][0];
    const f16* KtL = &KtD[cur][0];

    // issue next tile's global loads first (latency hides under compute)
    if (kt < kt1){
      int s0n = (kt+1) * 64;
      #pragma unroll
      for (int it = 0; it < 4; it++)
        sKb[it] = *(const half8*)(kg + (size_t)(s0n + sb_r + it*16)*DD + sb_c);
      #pragma unroll
      for (int it = 0; it < 4; it++)
        sKt[it] = *(const half8*)(ktg + (size_t)(st_r + it*32)*TT + s0n + st_c);
    }

    int s0 = kt * 64;
    // ---- QK^T: A = K rows (LDS b128), B = Q regs -> S^T[key32][q32] x2 ----
    f32x16 sa0, sa1;
    #pragma unroll
    for (int i = 0; i < 16; i++){ sa0[i] = 0.f; sa1[i] = 0.f; }
    #pragma unroll
    for (int ks = 0; ks < 8; ks++){
      half8 a0 = *(const half8*)(KbL + (q31)      *136 + 16*ks + 8*hi);
      half8 a1 = *(const half8*)(KbL + (32 + q31) *136 + 16*ks + 8*hi);
      sa0 = __builtin_amdgcn_mfma_f32_32x32x16_f16(a0, qb[ks], sa0, 0,0,0);
      sa1 = __builtin_amdgcn_mfma_f32_32x32x16_f16(a1, qb[ks], sa1, 0,0,0);
    }

    // ---- sin + causal mask, in-register ----
    float p0v[16], p1v[16];
    #pragma unroll
    for (int r = 0; r < 16; r++){
      int kr = (r&3) + 8*(r>>2) + 4*hi;
      p0v[r] = (s0 + kr      <= qrow_g) ? __sinf(sa0[r]) : 0.f;
      p1v[r] = (s0 + 32 + kr <= qrow_g) ? __sinf(sa1[r]) : 0.f;
    }

    // ---- in-register P regroup (cvt_pk + shfl_xor(32)) ----
    half8 pf[4];
    #pragma unroll
    for (int kb = 0; kb < 2; kb++){
      const float* pv = kb ? p1v : p0v;
      #pragma unroll
      for (int u = 0; u < 2; u++){
        int pl0 = pack2(pv[8*u+0], pv[8*u+1]);
        int pl1 = pack2(pv[8*u+2], pv[8*u+3]);
        int ph0 = pack2(pv[8*u+4], pv[8*u+5]);
        int ph1 = pack2(pv[8*u+6], pv[8*u+7]);
        int xl0 = __shfl_xor(pl0, 32);
        int xl1 = __shfl_xor(pl1, 32);
        int xh0 = __shfl_xor(ph0, 32);
        int xh1 = __shfl_xor(ph1, 32);
        i32x4 fr;
        fr[0] = hi ? xh0 : pl0;
        fr[1] = hi ? xh1 : pl1;
        fr[2] = hi ? ph0 : xl0;
        fr[3] = hi ? ph1 : xl1;
        pf[2*kb+u] = __builtin_bit_cast(half8, fr);
      }
    }

    // ---- PV swapped: A = Kt rows, B = P frags -> O^T[dim32][q32] x4 ----
    #pragma unroll
    for (int s = 0; s < 4; s++){
      #pragma unroll
      for (int d0 = 0; d0 < 4; d0++){
        half8 bf = *(const half8*)(KtL + (32*d0 + q31)*72 + 16*s + 8*hi);
        acc[d0] = __builtin_amdgcn_mfma_f32_32x32x16_f16(bf, pf[s], acc[d0], 0,0,0);
      }
    }

    // ---- write next tile into the other LDS buffer; single barrier per tile ----
    if (kt < kt1){
      f16* KbN = &KbD[cur^1][0];
      f16* KtN = &KtD[cur^1][0];
      #pragma unroll
      for (int it = 0; it < 4; it++)
        *(half8*)(KbN + (sb_r + it*16)*136 + sb_c) = sKb[it];
      #pragma unroll
      for (int it = 0; it < 4; it++)
        *(half8*)(KtN + (st_r + it*32)*72 + st_c) = sKt[it];
      __syncthreads();
    }
  }

  // ================= fused Wo projection: kur^T = Wo^T @ O^T =================
  __syncthreads();                 // all waves done reading Kb
  f16* WoL = &KbD[0][0];           // [odim][idim] fp16, stride 136 (spans both Kb buffers)
  {
    // coalesced copy of precomputed woT (32 KB, L2-resident) into LDS
    int j  = tid >> 1;             // odim row 0..127
    int ib = tid & 1;              // half 0/1
    const f16* src = woT + (size_t)j*DD + ib*64;
    f16* dst = WoL + j*136 + ib*64;
    #pragma unroll
    for (int u = 0; u < 8; u++)
      *(half8*)(dst + u*8) = *(const half8*)(src + u*8);
  }
  // O^T -> fp16 B-frags (register-only; overlaps staging latency)
  half8 bO[8];
  #pragma unroll
  for (int d0 = 0; d0 < 4; d0++){
    #pragma unroll
    for (int m = 0; m < 2; m++){
      int pl0 = pack2(acc[d0][8*m+0], acc[d0][8*m+1]);
      int pl1 = pack2(acc[d0][8*m+2], acc[d0][8*m+3]);
      int ph0 = pack2(acc[d0][8*m+4], acc[d0][8*m+5]);
      int ph1 = pack2(acc[d0][8*m+6], acc[d0][8*m+7]);
      int xl0 = __shfl_xor(pl0, 32);
      int xl1 = __shfl_xor(pl1, 32);
      int xh0 = __shfl_xor(ph0, 32);
      int xh1 = __shfl_xor(ph1, 32);
      i32x4 fr;
      fr[0] = hi ? xh0 : pl0;
      fr[1] = hi ? xh1 : pl1;
      fr[2] = hi ? ph0 : xl0;
      fr[3] = hi ? ph1 : xl1;
      bO[2*d0+m] = __builtin_bit_cast(half8, fr);
    }
  }
  __syncthreads();

  f32x16 acc2[4];
  #pragma unroll
  for (int ob = 0; ob < 4; ob++)
    #pragma unroll
    for (int i = 0; i < 16; i++) acc2[ob][i] = 0.f;
  #pragma unroll
  for (int ks = 0; ks < 8; ks++){
    #pragma unroll
    for (int ob = 0; ob < 4; ob++){
      half8 af = *(const half8*)(WoL + (32*ob + q31)*136 + 16*ks + 8*hi);
      acc2[ob] = __builtin_amdgcn_mfma_f32_32x32x16_f16(af, bO[ks], acc2[ob], 0,0,0);
    }
  }

  // ---- epilogue: kur partial store, part[q][odim]; b64-packed ----
  f16* pb = part + (size_t)bid*(QTILE*DD) + (size_t)(32*w + q31)*DD;
  #pragma unroll
  for (int ob = 0; ob < 4; ob++){
    #pragma unroll
    for (int j = 0; j < 4; j++){
      i32x2 pw = { pack2(acc2[ob][4*j+0], acc2[ob][4*j+1]),
                   pack2(acc2[ob][4*j+2], acc2[ob][4*j+3]) };
      *(i32x2*)(pb + 32*ob + 8*j + 4*hi) = pw;
    }
  }
}

// ====== k_comb5 (512 threads / 8 waves, 32 rows/block): split-K sum of fp16 kur partials;
//        tot = mf + kur + bo; tangent proj; RK4; retract; fused next-stage q-proj ======
__global__ __launch_bounds__(512) void k_comb5(
    const float* __restrict__ z, const float* __restrict__ bo,
    const float* __restrict__ mf, const f16* __restrict__ part,
    const float* __restrict__ zin, float* __restrict__ zout,
    float* __restrict__ vsum, float* __restrict__ out,
    const float* __restrict__ Wq, const float* __restrict__ bq, f16* __restrict__ qhb,
    float wsum, float cretr, int first, int last)
{
  __shared__ f16 Wqh[DD*DD];     // 32 KB (Wq, staged only when !last)
  __shared__ float As[32*DD];    // 16 KB
  int tid = threadIdx.x;
  int r0 = blockIdx.x * 32;
  if (!last){
    #pragma unroll
    for (int it = 0; it < 4; it++){
      int idx = tid + it*512;               // 2048 half8 chunks
      f32x4 a = *(const f32x4*)(Wq + (size_t)idx*8);
      f32x4 b = *(const f32x4*)(Wq + (size_t)idx*8 + 4);
      half8 h;
      #pragma unroll
      for (int u = 0; u < 4; u++){ h[u] = (f16)a[u]; h[4+u] = (f16)b[u]; }
      *(half8*)(Wqh + (size_t)idx*8) = h;
    }
  }
  // ---- inline split-K reduction of fp16 kur partials into As (rows r0..r0+31) ----
  {
    int b = r0 >> 12;
    int t = r0 & 4095;
    int qt = t >> 7;
    int ro = t & 127;
    int nc = (qt + 4) >> 2;       // ceil((qt+1)/4)
    int base = 0;                 // LPT reversed prefix: larger qt's chunks come first
    #pragma unroll 1
    for (int j = NQT3-1; j > qt; j--) base += (j + 4) >> 2;
    size_t sb = ((size_t)b*NCHUNK + base)*(QTILE*DD) + (size_t)ro*DD;
    // 512 half8 slots = 4096 elements (32 rows x 128 dims); one slot per thread
    const f16* s = part + sb + (size_t)tid*8;
    float a[8];
    {
      half8 v = *(const half8*)(s);
      #pragma unroll
      for (int u = 0; u < 8; u++) a[u] = (float)v[u];
    }
    for (int cc = 1; cc < nc; cc++){
      half8 v = *(const half8*)(s + (size_t)cc*(QTILE*DD));
      #pragma unroll
      for (int u = 0; u < 8; u++) a[u] += (float)v[u];
    }
    f32x4 o0v = {a[0],a[1],a[2],a[3]}, o1v = {a[4],a[5],a[6],a[7]};
    *(f32x4*)(As + (size_t)tid*8) = o0v;
    *(f32x4*)(As + (size_t)tid*8 + 4) = o1v;
  }
  __syncthreads();
  int c = tid & 15, rr = tid >> 4;    // 32 rows, 16 col-groups of 8
  float kur0[8];
  {
    f32x4 k0a = *(const f32x4*)(As + rr*DD + c*8);
    f32x4 k0b = *(const f32x4*)(As + rr*DD + c*8 + 4);
    #pragma unroll
    for (int u = 0; u < 4; u++){
      kur0[u] = k0a[u] + bo[c*8+u];
      kur0[4+u] = k0b[u] + bo[c*8+4+u];
    }
  }
  size_t o0 = (size_t)(r0+rr)*DD + c*8;
  float tot0[8], zi0[8];
  {
    f32x4 m0a = *(const f32x4*)(mf + o0), m0b = *(const f32x4*)(mf + o0 + 4);
    f32x4 z0a = *(const f32x4*)(zin + o0), z0b = *(const f32x4*)(zin + o0 + 4);
    #pragma unroll
    for (int u = 0; u < 4; u++){
      tot0[u] = m0a[u] + kur0[u]; tot0[4+u] = m0b[u] + kur0[4+u];
      zi0[u] = z0a[u]; zi0[4+u] = z0b[u];
    }
  }
  float p0 = 0.f;
  #pragma unroll
  for (int u = 0; u < 8; u++){ p0 = fmaf(tot0[u], zi0[u], p0); }
  #pragma unroll
  for (int m = 1; m < 16; m <<= 1){ p0 += __shfl_xor(p0, m, 16); }
  float ki0[8], vs0[8];
  #pragma unroll
  for (int u = 0; u < 8; u++){
    ki0[u] = tot0[u] - p0 * zi0[u];
  }
  if (first){
    #pragma unroll
    for (int u = 0; u < 8; u++){ vs0[u] = wsum*ki0[u]; }
  } else {
    f32x4 v0a = *(const f32x4*)(vsum + o0), v0b = *(const f32x4*)(vsum + o0 + 4);
    #pragma unroll
    for (int u = 0; u < 4; u++){
      vs0[u] = fmaf(wsum, ki0[u], v0a[u]); vs0[4+u] = fmaf(wsum, ki0[4+u], v0b[u]);
    }
  }
  if (!last){
    f32x4 va = {vs0[0],vs0[1],vs0[2],vs0[3]}, vb = {vs0[4],vs0[5],vs0[6],vs0[7]};
    *(f32x4*)(vsum + o0) = va; *(f32x4*)(vsum + o0 + 4) = vb;
  }
  float nz0[8];
  {
    f32x4 z0a = *(const f32x4*)(z + o0), z0b = *(const f32x4*)(z + o0 + 4);
    #pragma unroll
    for (int u = 0; u < 4; u++){
      float d0a = last ? vs0[u]*(1.f/6.f)   : cretr*ki0[u];
      float d0b = last ? vs0[4+u]*(1.f/6.f) : cretr*ki0[4+u];
      nz0[u] = z0a[u] + d0a; nz0[4+u] = z0b[u] + d0b;
    }
  }
  float n0 = 0.f;
  #pragma unroll
  for (int u = 0; u < 8; u++){ n0 = fmaf(nz0[u], nz0[u], n0); }
  #pragma unroll
  for (int m = 1; m < 16; m <<= 1){ n0 += __shfl_xor(n0, m, 16); }
  float i0 = 1.f / fmaxf(sqrtf(n0), 1e-8f);
  float* dst = last ? out : zout;
  f32x4 ra = {nz0[0]*i0, nz0[1]*i0, nz0[2]*i0, nz0[3]*i0};
  f32x4 rb = {nz0[4]*i0, nz0[5]*i0, nz0[6]*i0, nz0[7]*i0};
  *(f32x4*)(dst + o0) = ra; *(f32x4*)(dst + o0 + 4) = rb;

  // ---- fused q-projection for the NEXT stage: q_hat = normalize(zc @ Wq + bq) ----
  if (!last){
    __syncthreads();                      // all reads of As are done
    *(f32x4*)(As + rr*DD + c*8)     = ra;
    *(f32x4*)(As + rr*DD + c*8 + 4) = rb;
    __syncthreads();
    float q0[8];
    #pragma unroll
    for (int u = 0; u < 8; u++){ q0[u] = bq[c*8+u]; }
    const float* qr0 = As + rr*DD;
    #pragma unroll 4
    for (int i = 0; i < DD; i++){
      half8 wv = *(const half8*)(Wqh + i*DD + c*8);
      float a0 = qr0[i];
      #pragma unroll
      for (int u = 0; u < 8; u++){
        q0[u] = fmaf(a0, (float)wv[u], q0[u]);
      }
    }
    float s0 = 0.f;
    #pragma unroll
    for (int u = 0; u < 8; u++){ s0 = fmaf(q0[u], q0[u], s0); }
    #pragma unroll
    for (int m = 1; m < 16; m <<= 1){ s0 += __shfl_xor(s0, m, 16); }
    float qi0 = 1.f / fmaxf(sqrtf(s0), 1e-8f);
    half8 h0;
    #pragma unroll
    for (int u = 0; u < 8; u++){ h0[u] = (f16)(q0[u]*qi0); }
    *(half8*)(qhb + (size_t)(r0+rr)*DD + c*8) = h0;
  }
}

extern "C" void kernel_launch(void* const* d_in, const int* in_sizes, int n_in,
                              void* d_out, int out_size, void* d_ws, size_t ws_size,
                              hipStream_t stream) {
  const float* z  = (const float*)d_in[0];
  const float* ck = (const float*)d_in[1];
  const float* cb = (const float*)d_in[2];
  const float* Wq = (const float*)d_in[3];
  const float* bq = (const float*)d_in[4];
  const float* Wk = (const float*)d_in[5];
  const float* bk = (const float*)d_in[6];
  const float* Wo = (const float*)d_in[7];
  const float* bo = (const float*)d_in[8];
  float* out = (float*)d_out;

  float* mf   = (float*)d_ws;          // [B,T,D] f32
  float* zc   = mf   + NELT;
  float* vsum = zc   + NELT;
  f16*   khb  = (f16*)(vsum + NELT);   // fp16 [B,T,D]
  f16*   khT  = khb  + NELT;           // fp16 [B,D,T]
  f16*   qhb  = khT  + NELT;           // fp16 [B,T,D]
  f16*   part = qhb  + NELT;           // [BB*NCHUNK][128][128] fp16 kur partials (~9.4 MB)
  f16*   woT  = part + (size_t)BB*NCHUNK*QTILE*DD;   // fp16 WoT [128][128]

  k_prep<<<1025, 256, 0, stream>>>(z, Wk, bk, ck, cb, Wq, bq, Wo, khb, khT, qhb, mf, woT);

  const float wv[4] = {1.f, 2.f, 2.f, 1.f};
  const float cv[4] = {0.5f, 0.5f, 1.f, 0.f};
  for (int st = 0; st < 4; st++){
    const float* zcur = (st == 0) ? z : zc;
    k_attn22<<<BB*NCHUNK, 256, 0, stream>>>(qhb, khb, khT, woT, part);
    k_comb5 <<<NROW/32, 512, 0, stream>>>(z, bo, mf, part, zcur, zc, vsum, out,
                                          Wq, bq, qhb, wv[st], cv[st], st == 0, st == 3);
  }
}

// Round 13
// 260.590 us; speedup vs baseline: 1.1478x; 1.0021x over previous
//
#include <hip/hip_runtime.h>
#include <hip/hip_bf16.h>

#define BB 2
#define TT 4096
#define DD 128
#define KK 256
#define NROW (BB*TT)    // 8192 rows
#define NELT (NROW*DD)  // 1048576 elements per [B,T,D] buffer

typedef _Float16 f16;
typedef __attribute__((ext_vector_type(8))) f16 half8;
typedef __attribute__((ext_vector_type(2))) __fp16 fp16x2;
typedef __attribute__((ext_vector_type(4))) float f32x4;
typedef __attribute__((ext_vector_type(16))) float f32x16;
typedef __attribute__((ext_vector_type(2))) int i32x2;
typedef __attribute__((ext_vector_type(4))) int i32x4;

__device__ __forceinline__ int pack2(float a, float b){
  fp16x2 h = __builtin_amdgcn_cvt_pkrtz(a, b);
  return __builtin_bit_cast(int, h);
}

// ---- stage a 128x128 f32 weight matrix into LDS as fp16 (32 KB), 256 threads ----
__device__ __forceinline__ void stage_w_f16(int tid, const float* __restrict__ W, f16* Wh){
  #pragma unroll
  for (int it = 0; it < 8; it++){
    int idx = tid + it*256;               // 2048 half8 chunks
    f32x4 a = *(const f32x4*)(W + (size_t)idx*8);
    f32x4 b = *(const f32x4*)(W + (size_t)idx*8 + 4);
    half8 h;
    #pragma unroll
    for (int u = 0; u < 4; u++){ h[u] = (f16)a[u]; h[4+u] = (f16)b[u]; }
    *(half8*)(Wh + (size_t)idx*8) = h;
  }
}

// ---- shared helper: 32-row fp32 matvec (fp16 W in LDS) + normalize -> fp16 rows (+transpose)
__device__ __forceinline__ void proj_norm_rows(
    int tid, int r0,
    const float* __restrict__ src, const float* __restrict__ W, const float* __restrict__ bias,
    f16* __restrict__ dst, f16* __restrict__ dstT)
{
  __shared__ f16 Wh[DD*DD];      // 32 KB
  __shared__ float zs[32*DD];    // 16 KB
  stage_w_f16(tid, W, Wh);
  #pragma unroll
  for (int it = 0; it < 4; it++){
    int idx = tid + it*256;
    *(f32x4*)(zs + idx*4) = *(const f32x4*)(src + (size_t)r0*DD + idx*4);
  }
  __syncthreads();
  int c = tid & 15, rr = tid >> 4;
  float acc0[8], acc1[8];
  #pragma unroll
  for (int u = 0; u < 8; u++){ float bv = bias[c*8+u]; acc0[u] = bv; acc1[u] = bv; }
  const float* zr0 = zs + rr*DD;
  const float* zr1 = zs + (rr+16)*DD;
  #pragma unroll 4
  for (int i = 0; i < DD; i++){
    half8 wv = *(const half8*)(Wh + i*DD + c*8);
    float a0 = zr0[i], a1 = zr1[i];
    #pragma unroll
    for (int u = 0; u < 8; u++){
      float w = (float)wv[u];
      acc0[u] = fmaf(a0, w, acc0[u]);
      acc1[u] = fmaf(a1, w, acc1[u]);
    }
  }
  float s0 = 0.f, s1 = 0.f;
  #pragma unroll
  for (int u = 0; u < 8; u++){ s0 = fmaf(acc0[u], acc0[u], s0); s1 = fmaf(acc1[u], acc1[u], s1); }
  #pragma unroll
  for (int m = 1; m < 16; m <<= 1){ s0 += __shfl_xor(s0, m, 16); s1 += __shfl_xor(s1, m, 16); }
  float inv0 = 1.f / fmaxf(sqrtf(s0), 1e-8f);
  float inv1 = 1.f / fmaxf(sqrtf(s1), 1e-8f);
  half8 h0, h1;
  #pragma unroll
  for (int u = 0; u < 8; u++){ h0[u] = (f16)(acc0[u]*inv0); h1[u] = (f16)(acc1[u]*inv1); }
  int row0 = r0 + rr, row1 = row0 + 16;
  *(half8*)(dst + (size_t)row0*DD + c*8) = h0;
  *(half8*)(dst + (size_t)row1*DD + c*8) = h1;
  if (dstT){
    int b = row0 >> 12, t0 = row0 & 4095, t1 = row1 & 4095;
    #pragma unroll
    for (int u = 0; u < 8; u++){
      dstT[((size_t)b*DD + c*8 + u)*TT + t0] = h0[u];
      dstT[((size_t)b*DD + c*8 + u)*TT + t1] = h1[u];
    }
  }
}

// ======== k_prep: blocks 0..511: conv; 512..767: k-proj; 768..1023: q0-proj; 1024: WoT ==
__global__ __launch_bounds__(256) void k_prep(
    const float* __restrict__ z, const float* __restrict__ Wk, const float* __restrict__ bk,
    const float* __restrict__ ck, const float* __restrict__ cb,
    const float* __restrict__ Wq, const float* __restrict__ bq,
    const float* __restrict__ Wo,
    f16* __restrict__ khb, f16* __restrict__ khT, f16* __restrict__ qhb,
    float* __restrict__ mf, f16* __restrict__ woT)
{
  int tid = threadIdx.x;
  if (blockIdx.x < 512){
    int bid = blockIdx.x;
    int d = tid & 127, tg = tid >> 7;
    int b = bid >> 8;
    int tbase = ((bid & 255) << 4) + tg*8;
    const float* zb = z + (size_t)b*TT*DD;
    float acc[8];
    #pragma unroll
    for (int j = 0; j < 8; j++) acc[j] = 0.f;
    float ckq[8];
    #pragma unroll
    for (int u = 0; u < 8; u++) ckq[u] = 0.f;
    int sstart = tbase - (KK-1);
    for (int ch = 0; ch < 33; ch++){
      #pragma unroll
      for (int u = 0; u < 8; u++){
        int base = ch*8 + u;
        int s = sstart + base;
        float zv = ((unsigned)s < (unsigned)TT && base < 263) ? zb[(size_t)s*DD + d] : 0.f;
        ckq[u] = (base < KK) ? ck[(size_t)base*DD + d] : 0.f;
        #pragma unroll
        for (int j = 0; j < 8; j++) acc[j] = fmaf(ckq[(u-j)&7], zv, acc[j]);
      }
    }
    float cbv = cb[d];
    #pragma unroll
    for (int j = 0; j < 8; j++)
      mf[((size_t)b*TT + tbase + j)*DD + d] = acc[j] + cbv;
  } else if (blockIdx.x < 768){
    proj_norm_rows(tid, (blockIdx.x - 512) * 32, z, Wk, bk, khb, khT);
  } else if (blockIdx.x < 1024){
    proj_norm_rows(tid, (blockIdx.x - 768) * 32, z, Wq, bq, qhb, nullptr);
  } else {
    // ---- one-shot WoT fp16: woT[odim j][idim i] = Wo[i][j] ----
    int j  = tid >> 1;          // 0..127
    int ib = tid & 1;           // 0/1
    #pragma unroll
    for (int u = 0; u < 8; u++){
      int i0 = ib*64 + u*8;
      half8 h;
      #pragma unroll
      for (int k = 0; k < 8; k++) h[k] = (f16)Wo[(size_t)(i0+k)*DD + j];
      *(half8*)(woT + (size_t)j*DD + i0) = h;
    }
  }
}

// ====== MFMA attention v23: v22 + XCD-aware block swizzle (batch b -> XCDs 4b..4b+3) ======
#define QTILE 128
#define NQT3 (TT/QTILE)     // 32 q-tiles per batch
#define NCHUNK 144          // sum_{qt=0}^{31} ceil((qt+1)/4), chunks of 8 key-tiles (=36*4)

__global__ __launch_bounds__(256,2) void k_attn23(
    const f16* __restrict__ qhb, const f16* __restrict__ khb,
    const f16* __restrict__ khT, const f16* __restrict__ woT,
    f16* __restrict__ part)
{
  // ---- XCD swizzle: phys = g*8 + b*4 + r4, logical rem = g*4 + r4 (bijective on 288) ----
  // phys%8 = 4b + r4 -> batch 0 occupies XCDs 0..3, batch 1 occupies XCDs 4..7 (heuristic:
  // blockIdx round-robins over 8 XCDs). K/V working set per XCD ~5MB instead of ~10MB.
  int phys = blockIdx.x;
  int g    = phys >> 3;
  int low  = phys & 7;
  int b    = low >> 2;
  int rem  = g*4 + (low & 3);
  int bid  = b*NCHUNK + rem;     // logical id: part addressing (comb5 unchanged)
  int qt = 0, chunk = 0;
  #pragma unroll 1
  for (int j = NQT3-1; j >= 0; j--){
    int nch = (j + 4) >> 2;     // ceil((j+1)/4)
    if (rem < nch){ qt = j; chunk = rem; break; }
    rem -= nch;
  }
  int kt0 = chunk * 8;
  int kt1 = min(kt0 + 7, 2*qt + 1);
  int t0 = qt * QTILE;

  __shared__ __align__(16) f16 KbD[2][64*136];   // [key][dim], stride 136; reused as WoT LDS
  __shared__ __align__(16) f16 KtD[2][128*72];   // [dim][key], stride 72

  int tid  = threadIdx.x;
  int w    = tid >> 6;        // 4 waves, wave w owns q-rows 32w..32w+31
  int lane = tid & 63;
  int q31  = lane & 31;
  int hi   = lane >> 5;

  const f16* qg  = qhb + (size_t)b*TT*DD;
  const f16* kg  = khb + (size_t)b*TT*DD;
  const f16* ktg = khT + (size_t)b*DD*TT;

  int sb_r  = tid >> 4, sb_c = (tid & 15)*8;   // Kb staging
  int st_r  = tid >> 3, st_c = (tid & 7)*8;    // Kt staging

  int qrow_g = t0 + 32*w + q31;

  // Q fragments (B-operand): lane holds Q[qrow_g][16ks + 8hi + 0..7]
  half8 qb[8];
  {
    const f16* qrow = qg + (size_t)qrow_g*DD + 8*hi;
    #pragma unroll
    for (int ks = 0; ks < 8; ks++) qb[ks] = *(const half8*)(qrow + 16*ks);
  }

  // acc = O^T: acc[d0][r] = O^T[dim=32d0+(r&3)+8(r>>2)+4hi][q=q31]
  f32x16 acc[4];
  #pragma unroll
  for (int d = 0; d < 4; d++)
    #pragma unroll
    for (int i = 0; i < 16; i++) acc[d][i] = 0.f;

  // ---- prologue: stage first tile ----
  half8 sKb[4], sKt[4];
  {
    int s0 = kt0 * 64;
    #pragma unroll
    for (int it = 0; it < 4; it++)
      sKb[it] = *(const half8*)(kg + (size_t)(s0 + sb_r + it*16)*DD + sb_c);
    #pragma unroll
    for (int it = 0; it < 4; it++)
      sKt[it] = *(const half8*)(ktg + (size_t)(st_r + it*32)*TT + s0 + st_c);
    #pragma unroll
    for (int it = 0; it < 4; it++)
      *(half8*)(&KbD[0][0] + (sb_r + it*16)*136 + sb_c) = sKb[it];
    #pragma unroll
    for (int it = 0; it < 4; it++)
      *(half8*)(&KtD[0][0] + (st_r + it*32)*72 + st_c) = sKt[it];
  }
  __syncthreads();

  #pragma unroll 1
  for (int kt = kt0; kt <= kt1; kt++){
    int cur = (kt - kt0) & 1;
    const f16* KbL = &KbD[cur][0];
    const f16* KtL = &KtD[cur][0];

    // issue next tile's global loads first (latency hides under compute)
    if (kt < kt1){
      int s0n = (kt+1) * 64;
      #pragma unroll
      for (int it = 0; it < 4; it++)
        sKb[it] = *(const half8*)(kg + (size_t)(s0n + sb_r + it*16)*DD + sb_c);
      #pragma unroll
      for (int it = 0; it < 4; it++)
        sKt[it] = *(const half8*)(ktg + (size_t)(st_r + it*32)*TT + s0n + st_c);
    }

    int s0 = kt * 64;
    // ---- QK^T: A = K rows (LDS b128), B = Q regs -> S^T[key32][q32] x2 ----
    f32x16 sa0, sa1;
    #pragma unroll
    for (int i = 0; i < 16; i++){ sa0[i] = 0.f; sa1[i] = 0.f; }
    #pragma unroll
    for (int ks = 0; ks < 8; ks++){
      half8 a0 = *(const half8*)(KbL + (q31)      *136 + 16*ks + 8*hi);
      half8 a1 = *(const half8*)(KbL + (32 + q31) *136 + 16*ks + 8*hi);
      sa0 = __builtin_amdgcn_mfma_f32_32x32x16_f16(a0, qb[ks], sa0, 0,0,0);
      sa1 = __builtin_amdgcn_mfma_f32_32x32x16_f16(a1, qb[ks], sa1, 0,0,0);
    }

    // ---- sin + causal mask, in-register ----
    float p0v[16], p1v[16];
    #pragma unroll
    for (int r = 0; r < 16; r++){
      int kr = (r&3) + 8*(r>>2) + 4*hi;
      p0v[r] = (s0 + kr      <= qrow_g) ? __sinf(sa0[r]) : 0.f;
      p1v[r] = (s0 + 32 + kr <= qrow_g) ? __sinf(sa1[r]) : 0.f;
    }

    // ---- in-register P regroup (cvt_pk + shfl_xor(32)) ----
    half8 pf[4];
    #pragma unroll
    for (int kb = 0; kb < 2; kb++){
      const float* pv = kb ? p1v : p0v;
      #pragma unroll
      for (int u = 0; u < 2; u++){
        int pl0 = pack2(pv[8*u+0], pv[8*u+1]);
        int pl1 = pack2(pv[8*u+2], pv[8*u+3]);
        int ph0 = pack2(pv[8*u+4], pv[8*u+5]);
        int ph1 = pack2(pv[8*u+6], pv[8*u+7]);
        int xl0 = __shfl_xor(pl0, 32);
        int xl1 = __shfl_xor(pl1, 32);
        int xh0 = __shfl_xor(ph0, 32);
        int xh1 = __shfl_xor(ph1, 32);
        i32x4 fr;
        fr[0] = hi ? xh0 : pl0;
        fr[1] = hi ? xh1 : pl1;
        fr[2] = hi ? ph0 : xl0;
        fr[3] = hi ? ph1 : xl1;
        pf[2*kb+u] = __builtin_bit_cast(half8, fr);
      }
    }

    // ---- PV swapped: A = Kt rows, B = P frags -> O^T[dim32][q32] x4 ----
    #pragma unroll
    for (int s = 0; s < 4; s++){
      #pragma unroll
      for (int d0 = 0; d0 < 4; d0++){
        half8 bf = *(const half8*)(KtL + (32*d0 + q31)*72 + 16*s + 8*hi);
        acc[d0] = __builtin_amdgcn_mfma_f32_32x32x16_f16(bf, pf[s], acc[d0], 0,0,0);
      }
    }

    // ---- write next tile into the other LDS buffer; single barrier per tile ----
    if (kt < kt1){
      f16* KbN = &KbD[cur^1][0];
      f16* KtN = &KtD[cur^1][0];
      #pragma unroll
      for (int it = 0; it < 4; it++)
        *(half8*)(KbN + (sb_r + it*16)*136 + sb_c) = sKb[it];
      #pragma unroll
      for (int it = 0; it < 4; it++)
        *(half8*)(KtN + (st_r + it*32)*72 + st_c) = sKt[it];
      __syncthreads();
    }
  }

  // ================= fused Wo projection: kur^T = Wo^T @ O^T =================
  __syncthreads();                 // all waves done reading Kb
  f16* WoL = &KbD[0][0];           // [odim][idim] fp16, stride 136 (spans both Kb buffers)
  {
    // coalesced copy of precomputed woT (32 KB, L2-resident) into LDS
    int j  = tid >> 1;             // odim row 0..127
    int ib = tid & 1;              // half 0/1
    const f16* src = woT + (size_t)j*DD + ib*64;
    f16* dst = WoL + j*136 + ib*64;
    #pragma unroll
    for (int u = 0; u < 8; u++)
      *(half8*)(dst + u*8) = *(const half8*)(src + u*8);
  }
  // O^T -> fp16 B-frags (register-only; overlaps staging latency)
  half8 bO[8];
  #pragma unroll
  for (int d0 = 0; d0 < 4; d0++){
    #pragma unroll
    for (int m = 0; m < 2; m++){
      int pl0 = pack2(acc[d0][8*m+0], acc[d0][8*m+1]);
      int pl1 = pack2(acc[d0][8*m+2], acc[d0][8*m+3]);
      int ph0 = pack2(acc[d0][8*m+4], acc[d0][8*m+5]);
      int ph1 = pack2(acc[d0][8*m+6], acc[d0][8*m+7]);
      int xl0 = __shfl_xor(pl0, 32);
      int xl1 = __shfl_xor(pl1, 32);
      int xh0 = __shfl_xor(ph0, 32);
      int xh1 = __shfl_xor(ph1, 32);
      i32x4 fr;
      fr[0] = hi ? xh0 : pl0;
      fr[1] = hi ? xh1 : pl1;
      fr[2] = hi ? ph0 : xl0;
      fr[3] = hi ? ph1 : xl1;
      bO[2*d0+m] = __builtin_bit_cast(half8, fr);
    }
  }
  __syncthreads();

  f32x16 acc2[4];
  #pragma unroll
  for (int ob = 0; ob < 4; ob++)
    #pragma unroll
    for (int i = 0; i < 16; i++) acc2[ob][i] = 0.f;
  #pragma unroll
  for (int ks = 0; ks < 8; ks++){
    #pragma unroll
    for (int ob = 0; ob < 4; ob++){
      half8 af = *(const half8*)(WoL + (32*ob + q31)*136 + 16*ks + 8*hi);
      acc2[ob] = __builtin_amdgcn_mfma_f32_32x32x16_f16(af, bO[ks], acc2[ob], 0,0,0);
    }
  }

  // ---- epilogue: kur partial store, part[q][odim]; b64-packed (logical bid slot) ----
  f16* pb = part + (size_t)bid*(QTILE*DD) + (size_t)(32*w + q31)*DD;
  #pragma unroll
  for (int ob = 0; ob < 4; ob++){
    #pragma unroll
    for (int j = 0; j < 4; j++){
      i32x2 pw = { pack2(acc2[ob][4*j+0], acc2[ob][4*j+1]),
                   pack2(acc2[ob][4*j+2], acc2[ob][4*j+3]) };
      *(i32x2*)(pb + 32*ob + 8*j + 4*hi) = pw;
    }
  }
}

// ====== k_comb5 (512 threads / 8 waves, 32 rows/block): split-K sum of fp16 kur partials;
//        tot = mf + kur + bo; tangent proj; RK4; retract; fused next-stage q-proj ======
__global__ __launch_bounds__(512) void k_comb5(
    const float* __restrict__ z, const float* __restrict__ bo,
    const float* __restrict__ mf, const f16* __restrict__ part,
    const float* __restrict__ zin, float* __restrict__ zout,
    float* __restrict__ vsum, float* __restrict__ out,
    const float* __restrict__ Wq, const float* __restrict__ bq, f16* __restrict__ qhb,
    float wsum, float cretr, int first, int last)
{
  __shared__ f16 Wqh[DD*DD];     // 32 KB (Wq, staged only when !last)
  __shared__ float As[32*DD];    // 16 KB
  int tid = threadIdx.x;
  int r0 = blockIdx.x * 32;
  if (!last){
    #pragma unroll
    for (int it = 0; it < 4; it++){
      int idx = tid + it*512;               // 2048 half8 chunks
      f32x4 a = *(const f32x4*)(Wq + (size_t)idx*8);
      f32x4 b = *(const f32x4*)(Wq + (size_t)idx*8 + 4);
      half8 h;
      #pragma unroll
      for (int u = 0; u < 4; u++){ h[u] = (f16)a[u]; h[4+u] = (f16)b[u]; }
      *(half8*)(Wqh + (size_t)idx*8) = h;
    }
  }
  // ---- inline split-K reduction of fp16 kur partials into As (rows r0..r0+31) ----
  {
    int b = r0 >> 12;
    int t = r0 & 4095;
    int qt = t >> 7;
    int ro = t & 127;
    int nc = (qt + 4) >> 2;       // ceil((qt+1)/4)
    int base = 0;                 // LPT reversed prefix: larger qt's chunks come first
    #pragma unroll 1
    for (int j = NQT3-1; j > qt; j--) base += (j + 4) >> 2;
    size_t sb = ((size_t)b*NCHUNK + base)*(QTILE*DD) + (size_t)ro*DD;
    // 512 half8 slots = 4096 elements (32 rows x 128 dims); one slot per thread
    const f16* s = part + sb + (size_t)tid*8;
    float a[8];
    {
      half8 v = *(const half8*)(s);
      #pragma unroll
      for (int u = 0; u < 8; u++) a[u] = (float)v[u];
    }
    for (int cc = 1; cc < nc; cc++){
      half8 v = *(const half8*)(s + (size_t)cc*(QTILE*DD));
      #pragma unroll
      for (int u = 0; u < 8; u++) a[u] += (float)v[u];
    }
    f32x4 o0v = {a[0],a[1],a[2],a[3]}, o1v = {a[4],a[5],a[6],a[7]};
    *(f32x4*)(As + (size_t)tid*8) = o0v;
    *(f32x4*)(As + (size_t)tid*8 + 4) = o1v;
  }
  __syncthreads();
  int c = tid & 15, rr = tid >> 4;    // 32 rows, 16 col-groups of 8
  float kur0[8];
  {
    f32x4 k0a = *(const f32x4*)(As + rr*DD + c*8);
    f32x4 k0b = *(const f32x4*)(As + rr*DD + c*8 + 4);
    #pragma unroll
    for (int u = 0; u < 4; u++){
      kur0[u] = k0a[u] + bo[c*8+u];
      kur0[4+u] = k0b[u] + bo[c*8+4+u];
    }
  }
  size_t o0 = (size_t)(r0+rr)*DD + c*8;
  float tot0[8], zi0[8];
  {
    f32x4 m0a = *(const f32x4*)(mf + o0), m0b = *(const f32x4*)(mf + o0 + 4);
    f32x4 z0a = *(const f32x4*)(zin + o0), z0b = *(const f32x4*)(zin + o0 + 4);
    #pragma unroll
    for (int u = 0; u < 4; u++){
      tot0[u] = m0a[u] + kur0[u]; tot0[4+u] = m0b[u] + kur0[4+u];
      zi0[u] = z0a[u]; zi0[4+u] = z0b[u];
    }
  }
  float p0 = 0.f;
  #pragma unroll
  for (int u = 0; u < 8; u++){ p0 = fmaf(tot0[u], zi0[u], p0); }
  #pragma unroll
  for (int m = 1; m < 16; m <<= 1){ p0 += __shfl_xor(p0, m, 16); }
  float ki0[8], vs0[8];
  #pragma unroll
  for (int u = 0; u < 8; u++){
    ki0[u] = tot0[u] - p0 * zi0[u];
  }
  if (first){
    #pragma unroll
    for (int u = 0; u < 8; u++){ vs0[u] = wsum*ki0[u]; }
  } else {
    f32x4 v0a = *(const f32x4*)(vsum + o0), v0b = *(const f32x4*)(vsum + o0 + 4);
    #pragma unroll
    for (int u = 0; u < 4; u++){
      vs0[u] = fmaf(wsum, ki0[u], v0a[u]); vs0[4+u] = fmaf(wsum, ki0[4+u], v0b[u]);
    }
  }
  if (!last){
    f32x4 va = {vs0[0],vs0[1],vs0[2],vs0[3]}, vb = {vs0[4],vs0[5],vs0[6],vs0[7]};
    *(f32x4*)(vsum + o0) = va; *(f32x4*)(vsum + o0 + 4) = vb;
  }
  float nz0[8];
  {
    f32x4 z0a = *(const f32x4*)(z + o0), z0b = *(const f32x4*)(z + o0 + 4);
    #pragma unroll
    for (int u = 0; u < 4; u++){
      float d0a = last ? vs0[u]*(1.f/6.f)   : cretr*ki0[u];
      float d0b = last ? vs0[4+u]*(1.f/6.f) : cretr*ki0[4+u];
      nz0[u] = z0a[u] + d0a; nz0[4+u] = z0b[u] + d0b;
    }
  }
  float n0 = 0.f;
  #pragma unroll
  for (int u = 0; u < 8; u++){ n0 = fmaf(nz0[u], nz0[u], n0); }
  #pragma unroll
  for (int m = 1; m < 16; m <<= 1){ n0 += __shfl_xor(n0, m, 16); }
  float i0 = 1.f / fmaxf(sqrtf(n0), 1e-8f);
  float* dst = last ? out : zout;
  f32x4 ra = {nz0[0]*i0, nz0[1]*i0, nz0[2]*i0, nz0[3]*i0};
  f32x4 rb = {nz0[4]*i0, nz0[5]*i0, nz0[6]*i0, nz0[7]*i0};
  *(f32x4*)(dst + o0) = ra; *(f32x4*)(dst + o0 + 4) = rb;

  // ---- fused q-projection for the NEXT stage: q_hat = normalize(zc @ Wq + bq) ----
  if (!last){
    __syncthreads();                      // all reads of As are done
    *(f32x4*)(As + rr*DD + c*8)     = ra;
    *(f32x4*)(As + rr*DD + c*8 + 4) = rb;
    __syncthreads();
    float q0[8];
    #pragma unroll
    for (int u = 0; u < 8; u++){ q0[u] = bq[c*8+u]; }
    const float* qr0 = As + rr*DD;
    #pragma unroll 4
    for (int i = 0; i < DD; i++){
      half8 wv = *(const half8*)(Wqh + i*DD + c*8);
      float a0 = qr0[i];
      #pragma unroll
      for (int u = 0; u < 8; u++){
        q0[u] = fmaf(a0, (float)wv[u], q0[u]);
      }
    }
    float s0 = 0.f;
    #pragma unroll
    for (int u = 0; u < 8; u++){ s0 = fmaf(q0[u], q0[u], s0); }
    #pragma unroll
    for (int m = 1; m < 16; m <<= 1){ s0 += __shfl_xor(s0, m, 16); }
    float qi0 = 1.f / fmaxf(sqrtf(s0), 1e-8f);
    half8 h0;
    #pragma unroll
    for (int u = 0; u < 8; u++){ h0[u] = (f16)(q0[u]*qi0); }
    *(half8*)(qhb + (size_t)(r0+rr)*DD + c*8) = h0;
  }
}

extern "C" void kernel_launch(void* const* d_in, const int* in_sizes, int n_in,
                              void* d_out, int out_size, void* d_ws, size_t ws_size,
                              hipStream_t stream) {
  const float* z  = (const float*)d_in[0];
  const float* ck = (const float*)d_in[1];
  const float* cb = (const float*)d_in[2];
  const float* Wq = (const float*)d_in[3];
  const float* bq = (const float*)d_in[4];
  const float* Wk = (const float*)d_in[5];
  const float* bk = (const float*)d_in[6];
  const float* Wo = (const float*)d_in[7];
  const float* bo = (const float*)d_in[8];
  float* out = (float*)d_out;

  float* mf   = (float*)d_ws;          // [B,T,D] f32
  float* zc   = mf   + NELT;
  float* vsum = zc   + NELT;
  f16*   khb  = (f16*)(vsum + NELT);   // fp16 [B,T,D]
  f16*   khT  = khb  + NELT;           // fp16 [B,D,T]
  f16*   qhb  = khT  + NELT;           // fp16 [B,T,D]
  f16*   part = qhb  + NELT;           // [BB*NCHUNK][128][128] fp16 kur partials (~9.4 MB)
  f16*   woT  = part + (size_t)BB*NCHUNK*QTILE*DD;   // fp16 WoT [128][128]

  k_prep<<<1025, 256, 0, stream>>>(z, Wk, bk, ck, cb, Wq, bq, Wo, khb, khT, qhb, mf, woT);

  const float wv[4] = {1.f, 2.f, 2.f, 1.f};
  const float cv[4] = {0.5f, 0.5f, 1.f, 0.f};
  for (int st = 0; st < 4; st++){
    const float* zcur = (st == 0) ? z : zc;
    k_attn23<<<BB*NCHUNK, 256, 0, stream>>>(qhb, khb, khT, woT, part);
    k_comb5 <<<NROW/32, 512, 0, stream>>>(z, bo, mf, part, zcur, zc, vsum, out,
                                          Wq, bq, qhb, wv[st], cv[st], st == 0, st == 3);
  }
}